// Round 1
// baseline (381.904 us; speedup 1.0000x reference)
//
#include <hip/hip_runtime.h>
#include <hip/hip_bf16.h>

// Sizes (fixed for this problem)
// B=1, D=H=W=16 -> L=4096, C=96, d=96, K=6, N=16, R=6
#define L 4096
#define CDIM 96
#define DDIM 96
#define KDIR 6
#define NST 16
#define RRK 6
#define CPROJ 38   // R + 2N = 6+32

__device__ __forceinline__ float sigmoidf_(float x) { return 1.f / (1.f + __expf(-x)); }

// scan-position l -> spatial index s for base direction kb in {0,1,2}
__device__ __forceinline__ int sigma_k(int kb, int l) {
    if (kb == 0) return l;
    if (kb == 1) return ((l & 15) << 8) | ((l >> 8) << 4) | ((l >> 4) & 15);
    return (((l >> 4) & 15) << 8) | ((l & 15) << 4) | (l >> 8);
}

// K1: LayerNorm over C + in_proj (192x96). One block per spatial s, 192 threads.
// Outputs: xh_t[e*4096 + s] (e<96, channel-major for conv), zs[s*96 + e-96] = silu(z)
__global__ void k1_ln_inproj(const float* __restrict__ x, const float* __restrict__ ln_w,
                             const float* __restrict__ ln_b, const float* __restrict__ Wp,
                             float* __restrict__ xh_t, float* __restrict__ zs) {
    int s = blockIdx.x;
    int tid = threadIdx.x; // 192
    __shared__ float red0[128];
    __shared__ float red1[128];
    __shared__ __align__(16) float xn[96];
    const float* xr = x + s * CDIM;
    float v = (tid < 96) ? xr[tid] : 0.f;
    if (tid < 128) { red0[tid] = (tid < 96) ? v : 0.f; red1[tid] = (tid < 96) ? v * v : 0.f; }
    __syncthreads();
    for (int off = 64; off >= 1; off >>= 1) {
        if (tid < off) { red0[tid] += red0[tid + off]; red1[tid] += red1[tid + off]; }
        __syncthreads();
    }
    float mean = red0[0] * (1.f / 96.f);
    float var = red1[0] * (1.f / 96.f) - mean * mean;
    float rstd = rsqrtf(var + 1e-6f);
    if (tid < 96) xn[tid] = (v - mean) * rstd * ln_w[tid] + ln_b[tid];
    __syncthreads();
    // e = tid in [0,192)
    const float4* wr = (const float4*)(Wp + tid * 96);
    const float4* xn4 = (const float4*)xn;
    float acc = 0.f;
#pragma unroll
    for (int c4 = 0; c4 < 24; c4++) {
        float4 w4 = wr[c4]; float4 x4 = xn4[c4];
        acc += w4.x * x4.x + w4.y * x4.y + w4.z * x4.z + w4.w * x4.w;
    }
    if (tid < 96) xh_t[tid * L + s] = acc;
    else zs[s * 96 + (tid - 96)] = acc * sigmoidf_(acc);
}

// K2: depthwise 3x3x3 conv (SAME, cross-correlation) + bias + SiLU
__global__ void k2_conv(const float* __restrict__ xh_t, const float* __restrict__ cw,
                        const float* __restrict__ cb, float* __restrict__ xc) {
    int idx = blockIdx.x * 256 + threadIdx.x; // 96*4096
    int c = idx >> 12, s = idx & 4095;
    int dz = s >> 8, h = (s >> 4) & 15, w = s & 15;
    const float* xin = xh_t + c * L;
    const float* wc = cw + c * 27;
    float acc = cb[c];
#pragma unroll
    for (int i = 0; i < 3; i++) {
        int z2 = dz + i - 1; if ((unsigned)z2 > 15u) continue;
#pragma unroll
        for (int j = 0; j < 3; j++) {
            int h2 = h + j - 1; if ((unsigned)h2 > 15u) continue;
#pragma unroll
            for (int kk = 0; kk < 3; kk++) {
                int w2 = w + kk - 1; if ((unsigned)w2 > 15u) continue;
                acc += xin[z2 * 256 + h2 * 16 + w2] * wc[i * 9 + j * 3 + kk];
            }
        }
    }
    xc[c * L + s] = acc * sigmoidf_(acc);
}

// K3: Y[k][s][c] = sum_d x_proj_w[k][c][d] * xc[d][s]   (spatial layout, 38 c's)
__global__ void k3_xproj(const float* __restrict__ xc, const float* __restrict__ Wx,
                         float* __restrict__ Y) {
    int k = blockIdx.x;                      // 6
    int s = blockIdx.y * 256 + threadIdx.x;  // 16 blocks
    int ch = blockIdx.z;                     // 0/1 -> 19 c's each
    float acc[19];
#pragma unroll
    for (int i = 0; i < 19; i++) acc[i] = 0.f;
    const float* wk = Wx + (k * CPROJ + ch * 19) * DDIM;
    for (int dd = 0; dd < DDIM; dd++) {
        float v = xc[dd * L + s];
#pragma unroll
        for (int i = 0; i < 19; i++) acc[i] += wk[i * DDIM + dd] * v;
    }
    float* yo = Y + (k * L + s) * CPROJ + ch * 19;
#pragma unroll
    for (int i = 0; i < 19; i++) yo[i] = acc[i];
}

// K4: Zs[k][s][d] = softplus( sum_r dt_proj_w[k][d][r]*Y[k][s][r] + dt_proj_b[k][d] )
__global__ void k4_dt(const float* __restrict__ Y, const float* __restrict__ Wdt,
                      const float* __restrict__ bdt, float* __restrict__ Zs) {
    int k = blockIdx.x; int s = blockIdx.y; int dd = threadIdx.x; // 96
    const float* yr = Y + (k * L + s) * CPROJ;
    const float* wr = Wdt + (k * DDIM + dd) * RRK;
    float acc = bdt[k * DDIM + dd];
#pragma unroll
    for (int r = 0; r < RRK; r++) acc += wr[r] * yr[r];
    float sp = (acc > 20.f) ? acc : log1pf(__expf(acc));
    Zs[(k * L + s) * DDIM + dd] = sp;
}

// K5: chunked selective scan. Block per (k,d); 256 thr = 16 chunks x 16 states.
__global__ void __launch_bounds__(256) k5_scan(
        const float* __restrict__ Zs, const float* __restrict__ xc,
        const float* __restrict__ Y, const float* __restrict__ A_log,
        const float* __restrict__ D_skip, float* __restrict__ ys_buf) {
    int k = blockIdx.x;   // 6
    int dd = blockIdx.y;  // 96
    int tid = threadIdx.x;
    int n = tid & 15, ch = tid >> 4;
    int kb = (k < 3) ? k : (k - 3);
    bool flip = (k >= 3);
    float An = -__expf(A_log[(k * DDIM + dd) * NST + n]);
    float Dk = D_skip[k * DDIM + dd];
    __shared__ float la[16][16];
    __shared__ float lb[16][16];
    __shared__ float pb[16][16];
    const float* Zkd = Zs + (size_t)k * L * DDIM + dd;
    const float* xcd = xc + dd * L;
    const float* Yk = Y + (size_t)k * L * CPROJ;
    float a = 1.f, b = 0.f;
    int l0 = ch * 256;
    for (int i = 0; i < 256; i++) {
        int l = l0 + i;
        int lp = flip ? (4095 - l) : l;
        int s = sigma_k(kb, lp);
        float dt = Zkd[s * DDIM];
        float xv = xcd[s];
        float Bn = Yk[s * CPROJ + RRK + n];
        float dA = __expf(dt * An);
        b = dA * b + dt * xv * Bn;
        a *= dA;
    }
    la[ch][n] = a; lb[ch][n] = b;
    __syncthreads();
    if (tid < 16) {
        float rb = 0.f;
        for (int c = 0; c < 16; c++) { pb[c][tid] = rb; rb = la[c][tid] * rb + lb[c][tid]; }
    }
    __syncthreads();
    float h = pb[ch][n];
    for (int i = 0; i < 256; i++) {
        int l = l0 + i;
        int lp = flip ? (4095 - l) : l;
        int s = sigma_k(kb, lp);
        float dt = Zkd[s * DDIM];
        float xv = xcd[s];
        float Bn = Yk[s * CPROJ + RRK + n];
        float Cn = Yk[s * CPROJ + RRK + NST + n];
        float dA = __expf(dt * An);
        h = dA * h + dt * xv * Bn;
        float p = h * Cn;
        p += __shfl_xor(p, 1);
        p += __shfl_xor(p, 2);
        p += __shfl_xor(p, 4);
        p += __shfl_xor(p, 8);
        if (n == 0) ys_buf[((size_t)k * L + s) * DDIM + dd] = p + Dk * xv;
    }
}

// K6: sum 6 dirs + out LayerNorm + gate with silu(z) + out_proj + residual
__global__ void k6_out(const float* __restrict__ ys_buf, const float* __restrict__ zs,
                       const float* __restrict__ onw, const float* __restrict__ onb,
                       const float* __restrict__ Wo, const float* __restrict__ x,
                       float* __restrict__ out) {
    int s = blockIdx.x; int tid = threadIdx.x; // 96
    __shared__ float red0[128];
    __shared__ float red1[128];
    __shared__ __align__(16) float g[96];
    float v = 0.f;
#pragma unroll
    for (int k = 0; k < KDIR; k++) v += ys_buf[((size_t)k * L + s) * DDIM + tid];
    red0[tid] = v; red1[tid] = v * v;
    if (tid < 32) { red0[96 + tid] = 0.f; red1[96 + tid] = 0.f; }
    __syncthreads();
    for (int off = 64; off >= 1; off >>= 1) {
        if (tid < off) { red0[tid] += red0[tid + off]; red1[tid] += red1[tid + off]; }
        __syncthreads();
    }
    float mean = red0[0] * (1.f / 96.f);
    float var = red1[0] * (1.f / 96.f) - mean * mean;
    float rstd = rsqrtf(var + 1e-5f);
    g[tid] = ((v - mean) * rstd * onw[tid] + onb[tid]) * zs[s * 96 + tid];
    __syncthreads();
    const float4* wr = (const float4*)(Wo + tid * 96);
    const float4* g4 = (const float4*)g;
    float acc = x[s * 96 + tid];
#pragma unroll
    for (int c4 = 0; c4 < 24; c4++) {
        float4 w4 = wr[c4]; float4 x4 = g4[c4];
        acc += w4.x * x4.x + w4.y * x4.y + w4.z * x4.z + w4.w * x4.w;
    }
    out[s * 96 + tid] = acc;
}

extern "C" void kernel_launch(void* const* d_in, const int* in_sizes, int n_in,
                              void* d_out, int out_size, void* d_ws, size_t ws_size,
                              hipStream_t stream) {
    const float* x        = (const float*)d_in[0];
    const float* ln1_w    = (const float*)d_in[1];
    const float* ln1_b    = (const float*)d_in[2];
    const float* in_proj  = (const float*)d_in[3];
    const float* conv_w   = (const float*)d_in[4];
    const float* conv_b   = (const float*)d_in[5];
    const float* x_proj   = (const float*)d_in[6];
    const float* dt_w     = (const float*)d_in[7];
    const float* dt_b     = (const float*)d_in[8];
    const float* A_log    = (const float*)d_in[9];
    const float* D_skip   = (const float*)d_in[10];
    const float* onw      = (const float*)d_in[11];
    const float* onb      = (const float*)d_in[12];
    const float* out_w    = (const float*)d_in[13];
    float* out = (float*)d_out;

    float* xh_t = (float*)d_ws;              // 96*4096
    float* zs   = xh_t + 96 * L;             // 4096*96
    float* xc   = zs + 96 * L;               // 96*4096
    float* Y    = xc + 96 * L;               // 6*4096*38
    float* Zs   = Y + (size_t)KDIR * L * CPROJ;   // 6*4096*96
    float* ysb  = Zs + (size_t)KDIR * L * DDIM;   // 6*4096*96

    k1_ln_inproj<<<dim3(L), dim3(192), 0, stream>>>(x, ln1_w, ln1_b, in_proj, xh_t, zs);
    k2_conv<<<dim3(96 * L / 256), dim3(256), 0, stream>>>(xh_t, conv_w, conv_b, xc);
    k3_xproj<<<dim3(KDIR, 16, 2), dim3(256), 0, stream>>>(xc, x_proj, Y);
    k4_dt<<<dim3(KDIR, L), dim3(96), 0, stream>>>(Y, dt_w, dt_b, Zs);
    k5_scan<<<dim3(KDIR, DDIM), dim3(256), 0, stream>>>(Zs, xc, Y, A_log, D_skip, ysb);
    k6_out<<<dim3(L), dim3(96), 0, stream>>>(ysb, zs, onw, onb, out_w, x, out);
}

// Round 2
// 300.615 us; speedup vs baseline: 1.2704x; 1.2704x over previous
//
#include <hip/hip_runtime.h>
#include <hip/hip_bf16.h>

// Sizes (fixed for this problem)
// B=1, D=H=W=16 -> L=4096, C=96, d=96, K=6, N=16, R=6
#define L 4096
#define CDIM 96
#define DDIM 96
#define KDIR 6
#define NST 16
#define RRK 6
#define CPROJ 38   // R + 2N = 6+32

__device__ __forceinline__ float sigmoidf_(float x) { return 1.f / (1.f + __expf(-x)); }

// scan-position l -> spatial index s for base direction kb in {0,1,2}
__device__ __forceinline__ int sigma_k(int kb, int l) {
    if (kb == 0) return l;
    if (kb == 1) return ((l & 15) << 8) | ((l >> 8) << 4) | ((l >> 4) & 15);
    return (((l >> 4) & 15) << 8) | ((l & 15) << 4) | (l >> 8);
}

// K1: LayerNorm over C + in_proj (192x96). One block per spatial s, 192 threads.
__global__ void k1_ln_inproj(const float* __restrict__ x, const float* __restrict__ ln_w,
                             const float* __restrict__ ln_b, const float* __restrict__ Wp,
                             float* __restrict__ xh_t, float* __restrict__ zs) {
    int s = blockIdx.x;
    int tid = threadIdx.x; // 192
    __shared__ float red0[128];
    __shared__ float red1[128];
    __shared__ __align__(16) float xn[96];
    const float* xr = x + s * CDIM;
    float v = (tid < 96) ? xr[tid] : 0.f;
    if (tid < 128) { red0[tid] = (tid < 96) ? v : 0.f; red1[tid] = (tid < 96) ? v * v : 0.f; }
    __syncthreads();
    for (int off = 64; off >= 1; off >>= 1) {
        if (tid < off) { red0[tid] += red0[tid + off]; red1[tid] += red1[tid + off]; }
        __syncthreads();
    }
    float mean = red0[0] * (1.f / 96.f);
    float var = red1[0] * (1.f / 96.f) - mean * mean;
    float rstd = rsqrtf(var + 1e-6f);
    if (tid < 96) xn[tid] = (v - mean) * rstd * ln_w[tid] + ln_b[tid];
    __syncthreads();
    const float4* wr = (const float4*)(Wp + tid * 96);
    const float4* xn4 = (const float4*)xn;
    float acc = 0.f;
#pragma unroll
    for (int c4 = 0; c4 < 24; c4++) {
        float4 w4 = wr[c4]; float4 x4 = xn4[c4];
        acc += w4.x * x4.x + w4.y * x4.y + w4.z * x4.z + w4.w * x4.w;
    }
    if (tid < 96) xh_t[tid * L + s] = acc;
    else zs[s * 96 + (tid - 96)] = acc * sigmoidf_(acc);
}

// K2: depthwise 3x3x3 conv (SAME, cross-correlation) + bias + SiLU
__global__ void k2_conv(const float* __restrict__ xh_t, const float* __restrict__ cw,
                        const float* __restrict__ cb, float* __restrict__ xc) {
    int idx = blockIdx.x * 256 + threadIdx.x; // 96*4096
    int c = idx >> 12, s = idx & 4095;
    int dz = s >> 8, h = (s >> 4) & 15, w = s & 15;
    const float* xin = xh_t + c * L;
    const float* wc = cw + c * 27;
    float acc = cb[c];
#pragma unroll
    for (int i = 0; i < 3; i++) {
        int z2 = dz + i - 1; if ((unsigned)z2 > 15u) continue;
#pragma unroll
        for (int j = 0; j < 3; j++) {
            int h2 = h + j - 1; if ((unsigned)h2 > 15u) continue;
#pragma unroll
            for (int kk = 0; kk < 3; kk++) {
                int w2 = w + kk - 1; if ((unsigned)w2 > 15u) continue;
                acc += xin[z2 * 256 + h2 * 16 + w2] * wc[i * 9 + j * 3 + kk];
            }
        }
    }
    xc[c * L + s] = acc * sigmoidf_(acc);
}

// K3: Y[k][s][c] = sum_d x_proj_w[k][c][d] * xc[d][s]
__global__ void k3_xproj(const float* __restrict__ xc, const float* __restrict__ Wx,
                         float* __restrict__ Y) {
    int k = blockIdx.x;
    int s = blockIdx.y * 256 + threadIdx.x;
    int ch = blockIdx.z;
    float acc[19];
#pragma unroll
    for (int i = 0; i < 19; i++) acc[i] = 0.f;
    const float* wk = Wx + (k * CPROJ + ch * 19) * DDIM;
    for (int dd = 0; dd < DDIM; dd++) {
        float v = xc[dd * L + s];
#pragma unroll
        for (int i = 0; i < 19; i++) acc[i] += wk[i * DDIM + dd] * v;
    }
    float* yo = Y + (k * L + s) * CPROJ + ch * 19;
#pragma unroll
    for (int i = 0; i < 19; i++) yo[i] = acc[i];
}

// K4: Zs[k][s][d] = softplus( sum_r dt_proj_w[k][d][r]*Y[k][s][r] + dt_proj_b[k][d] )
__global__ void k4_dt(const float* __restrict__ Y, const float* __restrict__ Wdt,
                      const float* __restrict__ bdt, float* __restrict__ Zs) {
    int k = blockIdx.x; int s = blockIdx.y; int dd = threadIdx.x; // 96
    const float* yr = Y + (k * L + s) * CPROJ;
    const float* wr = Wdt + (k * DDIM + dd) * RRK;
    float acc = bdt[k * DDIM + dd];
#pragma unroll
    for (int r = 0; r < RRK; r++) acc += wr[r] * yr[r];
    float sp = (acc > 20.f) ? acc : log1pf(__expf(acc));
    Zs[(k * L + s) * DDIM + dd] = sp;
}

// K5 v2: chunked selective scan, 32 chunks x 128 positions.
// Block per (k,d); 256 thr = 16 thread-groups x 16 states; each thread runs
// TWO independent chains (chunks 2*ch and 2*ch+1) with unroll-4 batched loads.
__global__ void __launch_bounds__(256) k5_scan(
        const float* __restrict__ Zs, const float* __restrict__ xc,
        const float* __restrict__ Y, const float* __restrict__ A_log,
        const float* __restrict__ D_skip, float* __restrict__ ys_buf) {
    int k = blockIdx.x;   // 6
    int dd = blockIdx.y;  // 96
    int tid = threadIdx.x;
    int n = tid & 15, ch = tid >> 4;   // ch in [0,16)
    int kb = (k < 3) ? k : (k - 3);
    bool flip = (k >= 3);
    float An = -__expf(A_log[(k * DDIM + dd) * NST + n]);
    float Dk = D_skip[k * DDIM + dd];
    __shared__ float la[32][16];
    __shared__ float lb[32][16];
    __shared__ float pb[32][16];
    const float* Zkd = Zs + (size_t)k * L * DDIM + dd;
    const float* xcd = xc + dd * L;
    const float* Yk = Y + (size_t)k * L * CPROJ;

    int lbase0 = ch * 256;        // chain0: [lbase0, lbase0+128)
    int lbase1 = ch * 256 + 128;  // chain1: [lbase1, lbase1+128)

    float a0 = 1.f, b0 = 0.f, a1 = 1.f, b1 = 0.f;
    for (int i = 0; i < 128; i += 4) {
        int s0[4], s1[4];
        float dt0[4], xv0[4], B0[4], dt1[4], xv1[4], B1[4];
#pragma unroll
        for (int j = 0; j < 4; j++) {
            int lA = lbase0 + i + j, lB = lbase1 + i + j;
            int lpA = flip ? (4095 - lA) : lA;
            int lpB = flip ? (4095 - lB) : lB;
            s0[j] = sigma_k(kb, lpA);
            s1[j] = sigma_k(kb, lpB);
        }
#pragma unroll
        for (int j = 0; j < 4; j++) {
            dt0[j] = Zkd[(size_t)s0[j] * DDIM];
            xv0[j] = xcd[s0[j]];
            B0[j]  = Yk[s0[j] * CPROJ + RRK + n];
            dt1[j] = Zkd[(size_t)s1[j] * DDIM];
            xv1[j] = xcd[s1[j]];
            B1[j]  = Yk[s1[j] * CPROJ + RRK + n];
        }
#pragma unroll
        for (int j = 0; j < 4; j++) {
            float dA0 = __expf(dt0[j] * An);
            float dA1 = __expf(dt1[j] * An);
            b0 = dA0 * b0 + dt0[j] * xv0[j] * B0[j]; a0 *= dA0;
            b1 = dA1 * b1 + dt1[j] * xv1[j] * B1[j]; a1 *= dA1;
        }
    }
    la[2 * ch][n] = a0; lb[2 * ch][n] = b0;
    la[2 * ch + 1][n] = a1; lb[2 * ch + 1][n] = b1;
    __syncthreads();
    if (tid < 16) {
        float rb = 0.f;
#pragma unroll
        for (int c = 0; c < 32; c++) { pb[c][tid] = rb; rb = la[c][tid] * rb + lb[c][tid]; }
    }
    __syncthreads();
    float h0 = pb[2 * ch][n];
    float h1 = pb[2 * ch + 1][n];
    for (int i = 0; i < 128; i += 4) {
        int s0[4], s1[4];
        float dt0[4], xv0[4], B0[4], C0[4], dt1[4], xv1[4], B1[4], C1[4];
#pragma unroll
        for (int j = 0; j < 4; j++) {
            int lA = lbase0 + i + j, lB = lbase1 + i + j;
            int lpA = flip ? (4095 - lA) : lA;
            int lpB = flip ? (4095 - lB) : lB;
            s0[j] = sigma_k(kb, lpA);
            s1[j] = sigma_k(kb, lpB);
        }
#pragma unroll
        for (int j = 0; j < 4; j++) {
            dt0[j] = Zkd[(size_t)s0[j] * DDIM];
            xv0[j] = xcd[s0[j]];
            B0[j]  = Yk[s0[j] * CPROJ + RRK + n];
            C0[j]  = Yk[s0[j] * CPROJ + RRK + NST + n];
            dt1[j] = Zkd[(size_t)s1[j] * DDIM];
            xv1[j] = xcd[s1[j]];
            B1[j]  = Yk[s1[j] * CPROJ + RRK + n];
            C1[j]  = Yk[s1[j] * CPROJ + RRK + NST + n];
        }
#pragma unroll
        for (int j = 0; j < 4; j++) {
            float dA0 = __expf(dt0[j] * An);
            float dA1 = __expf(dt1[j] * An);
            h0 = dA0 * h0 + dt0[j] * xv0[j] * B0[j];
            h1 = dA1 * h1 + dt1[j] * xv1[j] * B1[j];
            float p0 = h0 * C0[j];
            float p1 = h1 * C1[j];
            p0 += __shfl_xor(p0, 1);  p1 += __shfl_xor(p1, 1);
            p0 += __shfl_xor(p0, 2);  p1 += __shfl_xor(p1, 2);
            p0 += __shfl_xor(p0, 4);  p1 += __shfl_xor(p1, 4);
            p0 += __shfl_xor(p0, 8);  p1 += __shfl_xor(p1, 8);
            if (n == 0) {
                ys_buf[((size_t)k * L + s0[j]) * DDIM + dd] = p0 + Dk * xv0[j];
                ys_buf[((size_t)k * L + s1[j]) * DDIM + dd] = p1 + Dk * xv1[j];
            }
        }
    }
}

// K6: sum 6 dirs + out LayerNorm + gate with silu(z) + out_proj + residual
__global__ void k6_out(const float* __restrict__ ys_buf, const float* __restrict__ zs,
                       const float* __restrict__ onw, const float* __restrict__ onb,
                       const float* __restrict__ Wo, const float* __restrict__ x,
                       float* __restrict__ out) {
    int s = blockIdx.x; int tid = threadIdx.x; // 96
    __shared__ float red0[128];
    __shared__ float red1[128];
    __shared__ __align__(16) float g[96];
    float v = 0.f;
#pragma unroll
    for (int k = 0; k < KDIR; k++) v += ys_buf[((size_t)k * L + s) * DDIM + tid];
    red0[tid] = v; red1[tid] = v * v;
    if (tid < 32) { red0[96 + tid] = 0.f; red1[96 + tid] = 0.f; }
    __syncthreads();
    for (int off = 64; off >= 1; off >>= 1) {
        if (tid < off) { red0[tid] += red0[tid + off]; red1[tid] += red1[tid + off]; }
        __syncthreads();
    }
    float mean = red0[0] * (1.f / 96.f);
    float var = red1[0] * (1.f / 96.f) - mean * mean;
    float rstd = rsqrtf(var + 1e-5f);
    g[tid] = ((v - mean) * rstd * onw[tid] + onb[tid]) * zs[s * 96 + tid];
    __syncthreads();
    const float4* wr = (const float4*)(Wo + tid * 96);
    const float4* g4 = (const float4*)g;
    float acc = x[s * 96 + tid];
#pragma unroll
    for (int c4 = 0; c4 < 24; c4++) {
        float4 w4 = wr[c4]; float4 x4 = g4[c4];
        acc += w4.x * x4.x + w4.y * x4.y + w4.z * x4.z + w4.w * x4.w;
    }
    out[s * 96 + tid] = acc;
}

extern "C" void kernel_launch(void* const* d_in, const int* in_sizes, int n_in,
                              void* d_out, int out_size, void* d_ws, size_t ws_size,
                              hipStream_t stream) {
    const float* x        = (const float*)d_in[0];
    const float* ln1_w    = (const float*)d_in[1];
    const float* ln1_b    = (const float*)d_in[2];
    const float* in_proj  = (const float*)d_in[3];
    const float* conv_w   = (const float*)d_in[4];
    const float* conv_b   = (const float*)d_in[5];
    const float* x_proj   = (const float*)d_in[6];
    const float* dt_w     = (const float*)d_in[7];
    const float* dt_b     = (const float*)d_in[8];
    const float* A_log    = (const float*)d_in[9];
    const float* D_skip   = (const float*)d_in[10];
    const float* onw      = (const float*)d_in[11];
    const float* onb      = (const float*)d_in[12];
    const float* out_w    = (const float*)d_in[13];
    float* out = (float*)d_out;

    float* xh_t = (float*)d_ws;              // 96*4096
    float* zs   = xh_t + 96 * L;             // 4096*96
    float* xc   = zs + 96 * L;               // 96*4096
    float* Y    = xc + 96 * L;               // 6*4096*38
    float* Zs   = Y + (size_t)KDIR * L * CPROJ;   // 6*4096*96
    float* ysb  = Zs + (size_t)KDIR * L * DDIM;   // 6*4096*96

    k1_ln_inproj<<<dim3(L), dim3(192), 0, stream>>>(x, ln1_w, ln1_b, in_proj, xh_t, zs);
    k2_conv<<<dim3(96 * L / 256), dim3(256), 0, stream>>>(xh_t, conv_w, conv_b, xc);
    k3_xproj<<<dim3(KDIR, 16, 2), dim3(256), 0, stream>>>(xc, x_proj, Y);
    k4_dt<<<dim3(KDIR, L), dim3(96), 0, stream>>>(Y, dt_w, dt_b, Zs);
    k5_scan<<<dim3(KDIR, DDIM), dim3(256), 0, stream>>>(Zs, xc, Y, A_log, D_skip, ysb);
    k6_out<<<dim3(L), dim3(96), 0, stream>>>(ysb, zs, onw, onb, out_w, x, out);
}

// Round 3
// 271.748 us; speedup vs baseline: 1.4054x; 1.1062x over previous
//
#include <hip/hip_runtime.h>
#include <hip/hip_bf16.h>

// Sizes (fixed): B=1, D=H=W=16 -> L=4096, C=96, d=96, K=6, N=16, R=6
#define L 4096
#define CDIM 96
#define DDIM 96
#define KDIR 6
#define NST 16
#define RRK 6
#define CPROJ 38   // R + 2N
#define NCHUNK 64
#define CHLEN 64   // NCHUNK*CHLEN == L

__device__ __forceinline__ float sigmoidf_(float x) { return 1.f / (1.f + __expf(-x)); }

// scan-position l -> spatial index s for base direction kb in {0,1,2}
__device__ __forceinline__ int sigma_k(int kb, int l) {
    if (kb == 0) return l;
    if (kb == 1) return ((l & 15) << 8) | ((l >> 8) << 4) | ((l >> 4) & 15);
    return (((l >> 4) & 15) << 8) | ((l & 15) << 4) | (l >> 8);
}

// K1: LayerNorm over C + in_proj (192x96). One block per spatial s, 192 threads.
__global__ void k1_ln_inproj(const float* __restrict__ x, const float* __restrict__ ln_w,
                             const float* __restrict__ ln_b, const float* __restrict__ Wp,
                             float* __restrict__ xh_t, float* __restrict__ zs) {
    int s = blockIdx.x;
    int tid = threadIdx.x; // 192
    __shared__ float red0[128];
    __shared__ float red1[128];
    __shared__ __align__(16) float xn[96];
    const float* xr = x + s * CDIM;
    float v = (tid < 96) ? xr[tid] : 0.f;
    if (tid < 128) { red0[tid] = (tid < 96) ? v : 0.f; red1[tid] = (tid < 96) ? v * v : 0.f; }
    __syncthreads();
    for (int off = 64; off >= 1; off >>= 1) {
        if (tid < off) { red0[tid] += red0[tid + off]; red1[tid] += red1[tid + off]; }
        __syncthreads();
    }
    float mean = red0[0] * (1.f / 96.f);
    float var = red1[0] * (1.f / 96.f) - mean * mean;
    float rstd = rsqrtf(var + 1e-6f);
    if (tid < 96) xn[tid] = (v - mean) * rstd * ln_w[tid] + ln_b[tid];
    __syncthreads();
    const float4* wr = (const float4*)(Wp + tid * 96);
    const float4* xn4 = (const float4*)xn;
    float acc = 0.f;
#pragma unroll
    for (int c4 = 0; c4 < 24; c4++) {
        float4 w4 = wr[c4]; float4 x4 = xn4[c4];
        acc += w4.x * x4.x + w4.y * x4.y + w4.z * x4.z + w4.w * x4.w;
    }
    if (tid < 96) xh_t[tid * L + s] = acc;
    else zs[s * 96 + (tid - 96)] = acc * sigmoidf_(acc);
}

// K2: depthwise 3x3x3 conv (SAME) + bias + SiLU
__global__ void k2_conv(const float* __restrict__ xh_t, const float* __restrict__ cw,
                        const float* __restrict__ cb, float* __restrict__ xc) {
    int idx = blockIdx.x * 256 + threadIdx.x; // 96*4096
    int c = idx >> 12, s = idx & 4095;
    int dz = s >> 8, h = (s >> 4) & 15, w = s & 15;
    const float* xin = xh_t + c * L;
    const float* wc = cw + c * 27;
    float acc = cb[c];
#pragma unroll
    for (int i = 0; i < 3; i++) {
        int z2 = dz + i - 1; if ((unsigned)z2 > 15u) continue;
#pragma unroll
        for (int j = 0; j < 3; j++) {
            int h2 = h + j - 1; if ((unsigned)h2 > 15u) continue;
#pragma unroll
            for (int kk = 0; kk < 3; kk++) {
                int w2 = w + kk - 1; if ((unsigned)w2 > 15u) continue;
                acc += xin[z2 * 256 + h2 * 16 + w2] * wc[i * 9 + j * 3 + kk];
            }
        }
    }
    xc[c * L + s] = acc * sigmoidf_(acc);
}

// K3: Y[k][s][c] = sum_d x_proj_w[k][c][d] * xc[d][s], unroll-4 batched loads
__global__ void k3_xproj(const float* __restrict__ xc, const float* __restrict__ Wx,
                         float* __restrict__ Y) {
    int k = blockIdx.x;
    int s = blockIdx.y * 256 + threadIdx.x;
    int ch = blockIdx.z;
    float acc[19];
#pragma unroll
    for (int i = 0; i < 19; i++) acc[i] = 0.f;
    const float* wk = Wx + (k * CPROJ + ch * 19) * DDIM;
    for (int dd = 0; dd < 96; dd += 4) {
        float v[4];
#pragma unroll
        for (int j = 0; j < 4; j++) v[j] = xc[(dd + j) * L + s];
#pragma unroll
        for (int j = 0; j < 4; j++)
#pragma unroll
            for (int i = 0; i < 19; i++) acc[i] += wk[i * DDIM + dd + j] * v[j];
    }
    float* yo = Y + (k * L + s) * CPROJ + ch * 19;
#pragma unroll
    for (int i = 0; i < 19; i++) yo[i] = acc[i];
}

// K4 flat: Zs[k][s][d] = softplus( sum_r Wdt[k][d][r]*Y[k][s][r] + bdt[k][d] )
__global__ void k4_dt(const float* __restrict__ Y, const float* __restrict__ Wdt,
                      const float* __restrict__ bdt, float* __restrict__ Zs) {
    int idx = blockIdx.x * 256 + threadIdx.x;   // < 6*4096*96
    int d = idx % 96;
    int rest = idx / 96;
    int s = rest & 4095;
    int k = rest >> 12;
    const float* yr = Y + (k * L + s) * CPROJ;
    const float* wr = Wdt + (k * DDIM + d) * RRK;
    float acc = bdt[k * DDIM + d];
#pragma unroll
    for (int r = 0; r < RRK; r++) acc += wr[r] * yr[r];
    float sp = (acc > 20.f) ? acc : log1pf(__expf(acc));
    Zs[idx] = sp;
}

// ---- 3-phase chunked selective scan ----
// Thread mapping (ka/kc): 256 thr = n (tid&15, minor) x dg (tid>>4);  d = dblk*16+dg
// Chunk c covers l in [c*64, c*64+64). Per-chunk state layout: [k][chunk][d][n]

// Phase A: per-chunk local scan -> (a = prod dA, b = local end state)
__global__ void __launch_bounds__(256) ka_scan(
        const float* __restrict__ Zs, const float* __restrict__ xc,
        const float* __restrict__ Y, const float* __restrict__ A_log,
        float* __restrict__ Aa, float* __restrict__ Ab) {
    int k = blockIdx.x;        // 6
    int chunk = blockIdx.y;    // 64
    int dblk = blockIdx.z;     // 6
    int tid = threadIdx.x;
    int n = tid & 15, dg = tid >> 4;
    int d = dblk * 16 + dg;
    int kb = (k < 3) ? k : (k - 3);
    bool flip = (k >= 3);
    float An = -__expf(A_log[(k * DDIM + d) * NST + n]);
    const float* Zk = Zs + (size_t)k * L * DDIM;
    const float* xcd = xc + d * L;
    const float* Yk = Y + (size_t)k * L * CPROJ;
    int l0 = chunk * CHLEN;
    float a = 1.f, b = 0.f;
    for (int i = 0; i < CHLEN; i += 4) {
        int sI[4]; float dt[4], xv[4], Bv[4];
#pragma unroll
        for (int j = 0; j < 4; j++) {
            int l = l0 + i + j;
            int lp = flip ? (4095 - l) : l;
            sI[j] = sigma_k(kb, lp);
        }
#pragma unroll
        for (int j = 0; j < 4; j++) {
            dt[j] = Zk[(size_t)sI[j] * DDIM + d];
            xv[j] = xcd[sI[j]];
            Bv[j] = Yk[sI[j] * CPROJ + RRK + n];
        }
#pragma unroll
        for (int j = 0; j < 4; j++) {
            float dA = __expf(dt[j] * An);
            b = dA * b + dt[j] * xv[j] * Bv[j];
            a *= dA;
        }
    }
    size_t o = (((size_t)k * NCHUNK + chunk) * DDIM + d) * NST + n;
    Aa[o] = a; Ab[o] = b;
}

// Phase B: serial combine across chunks, write exclusive-prefix carry
__global__ void __launch_bounds__(256) kb_combine(
        const float* __restrict__ Aa, const float* __restrict__ Ab,
        float* __restrict__ Pb) {
    int k = blockIdx.x;    // 6
    int dblk = blockIdx.y; // 6
    int tid = threadIdx.x;
    int n = tid & 15, dg = tid >> 4;
    int d = dblk * 16 + dg;
    size_t base = ((size_t)k * NCHUNK * DDIM + d) * NST + n;
    const size_t cstride = (size_t)DDIM * NST;
    float rb = 0.f;
    for (int c0 = 0; c0 < NCHUNK; c0 += 8) {
        float av[8], bv[8];
#pragma unroll
        for (int j = 0; j < 8; j++) {
            av[j] = Aa[base + (size_t)(c0 + j) * cstride];
            bv[j] = Ab[base + (size_t)(c0 + j) * cstride];
        }
#pragma unroll
        for (int j = 0; j < 8; j++) {
            Pb[base + (size_t)(c0 + j) * cstride] = rb;
            rb = av[j] * rb + bv[j];
        }
    }
}

// Phase C: re-scan chunk with carry, fuse y = sum_n h*C + D*x, write ys
__global__ void __launch_bounds__(256) kc_apply(
        const float* __restrict__ Zs, const float* __restrict__ xc,
        const float* __restrict__ Y, const float* __restrict__ A_log,
        const float* __restrict__ D_skip, const float* __restrict__ Pb,
        float* __restrict__ ys_buf) {
    int k = blockIdx.x;
    int chunk = blockIdx.y;
    int dblk = blockIdx.z;
    int tid = threadIdx.x;
    int n = tid & 15, dg = tid >> 4;
    int d = dblk * 16 + dg;
    int kb = (k < 3) ? k : (k - 3);
    bool flip = (k >= 3);
    float An = -__expf(A_log[(k * DDIM + d) * NST + n]);
    float Dk = D_skip[k * DDIM + d];
    const float* Zk = Zs + (size_t)k * L * DDIM;
    const float* xcd = xc + d * L;
    const float* Yk = Y + (size_t)k * L * CPROJ;
    float* ysk = ys_buf + (size_t)k * L * DDIM;
    float h = Pb[(((size_t)k * NCHUNK + chunk) * DDIM + d) * NST + n];
    int l0 = chunk * CHLEN;
    for (int i = 0; i < CHLEN; i += 4) {
        int sI[4]; float dt[4], xv[4], Bv[4], Cv[4];
#pragma unroll
        for (int j = 0; j < 4; j++) {
            int l = l0 + i + j;
            int lp = flip ? (4095 - l) : l;
            sI[j] = sigma_k(kb, lp);
        }
#pragma unroll
        for (int j = 0; j < 4; j++) {
            dt[j] = Zk[(size_t)sI[j] * DDIM + d];
            xv[j] = xcd[sI[j]];
            Bv[j] = Yk[sI[j] * CPROJ + RRK + n];
            Cv[j] = Yk[sI[j] * CPROJ + RRK + NST + n];
        }
#pragma unroll
        for (int j = 0; j < 4; j++) {
            float dA = __expf(dt[j] * An);
            h = dA * h + dt[j] * xv[j] * Bv[j];
            float p = h * Cv[j];
            p += __shfl_xor(p, 1);
            p += __shfl_xor(p, 2);
            p += __shfl_xor(p, 4);
            p += __shfl_xor(p, 8);
            if (n == 0) ysk[(size_t)sI[j] * DDIM + d] = p + Dk * xv[j];
        }
    }
}

// K6: sum 6 dirs + out LayerNorm + gate with silu(z) + out_proj + residual
__global__ void k6_out(const float* __restrict__ ys_buf, const float* __restrict__ zs,
                       const float* __restrict__ onw, const float* __restrict__ onb,
                       const float* __restrict__ Wo, const float* __restrict__ x,
                       float* __restrict__ out) {
    int s = blockIdx.x; int tid = threadIdx.x; // 96
    __shared__ float red0[128];
    __shared__ float red1[128];
    __shared__ __align__(16) float g[96];
    float v = 0.f;
#pragma unroll
    for (int k = 0; k < KDIR; k++) v += ys_buf[((size_t)k * L + s) * DDIM + tid];
    red0[tid] = v; red1[tid] = v * v;
    if (tid < 32) { red0[96 + tid] = 0.f; red1[96 + tid] = 0.f; }
    __syncthreads();
    for (int off = 64; off >= 1; off >>= 1) {
        if (tid < off) { red0[tid] += red0[tid + off]; red1[tid] += red1[tid + off]; }
        __syncthreads();
    }
    float mean = red0[0] * (1.f / 96.f);
    float var = red1[0] * (1.f / 96.f) - mean * mean;
    float rstd = rsqrtf(var + 1e-5f);
    g[tid] = ((v - mean) * rstd * onw[tid] + onb[tid]) * zs[s * 96 + tid];
    __syncthreads();
    const float4* wr = (const float4*)(Wo + tid * 96);
    const float4* g4 = (const float4*)g;
    float acc = x[s * 96 + tid];
#pragma unroll
    for (int c4 = 0; c4 < 24; c4++) {
        float4 w4 = wr[c4]; float4 x4 = g4[c4];
        acc += w4.x * x4.x + w4.y * x4.y + w4.z * x4.z + w4.w * x4.w;
    }
    out[s * 96 + tid] = acc;
}

extern "C" void kernel_launch(void* const* d_in, const int* in_sizes, int n_in,
                              void* d_out, int out_size, void* d_ws, size_t ws_size,
                              hipStream_t stream) {
    const float* x        = (const float*)d_in[0];
    const float* ln1_w    = (const float*)d_in[1];
    const float* ln1_b    = (const float*)d_in[2];
    const float* in_proj  = (const float*)d_in[3];
    const float* conv_w   = (const float*)d_in[4];
    const float* conv_b   = (const float*)d_in[5];
    const float* x_proj   = (const float*)d_in[6];
    const float* dt_w     = (const float*)d_in[7];
    const float* dt_b     = (const float*)d_in[8];
    const float* A_log    = (const float*)d_in[9];
    const float* D_skip   = (const float*)d_in[10];
    const float* onw      = (const float*)d_in[11];
    const float* onb      = (const float*)d_in[12];
    const float* out_w    = (const float*)d_in[13];
    float* out = (float*)d_out;

    float* xh_t = (float*)d_ws;                     // 96*4096
    float* zs   = xh_t + 96 * L;                    // 4096*96
    float* xc   = zs + 96 * L;                      // 96*4096
    float* Y    = xc + 96 * L;                      // 6*4096*38
    float* Zs   = Y + (size_t)KDIR * L * CPROJ;     // 6*4096*96
    float* ysb  = Zs + (size_t)KDIR * L * DDIM;     // 6*4096*96
    float* Aa   = ysb + (size_t)KDIR * L * DDIM;    // 6*64*96*16
    float* Ab   = Aa + (size_t)KDIR * NCHUNK * DDIM * NST;
    float* Pb   = Ab + (size_t)KDIR * NCHUNK * DDIM * NST;

    k1_ln_inproj<<<dim3(L), dim3(192), 0, stream>>>(x, ln1_w, ln1_b, in_proj, xh_t, zs);
    k2_conv<<<dim3(96 * L / 256), dim3(256), 0, stream>>>(xh_t, conv_w, conv_b, xc);
    k3_xproj<<<dim3(KDIR, 16, 2), dim3(256), 0, stream>>>(xc, x_proj, Y);
    k4_dt<<<dim3(KDIR * L * DDIM / 256), dim3(256), 0, stream>>>(Y, dt_w, dt_b, Zs);
    ka_scan<<<dim3(KDIR, NCHUNK, 6), dim3(256), 0, stream>>>(Zs, xc, Y, A_log, Aa, Ab);
    kb_combine<<<dim3(KDIR, 6), dim3(256), 0, stream>>>(Aa, Ab, Pb);
    kc_apply<<<dim3(KDIR, NCHUNK, 6), dim3(256), 0, stream>>>(Zs, xc, Y, A_log, D_skip, Pb, ysb);
    k6_out<<<dim3(L), dim3(96), 0, stream>>>(ysb, zs, onw, onb, out_w, x, out);
}

// Round 4
// 266.311 us; speedup vs baseline: 1.4341x; 1.0204x over previous
//
#include <hip/hip_runtime.h>
#include <hip/hip_bf16.h>

// Sizes (fixed): B=1, D=H=W=16 -> L=4096, C=96, d=96, K=6, N=16, R=6
#define L 4096
#define CDIM 96
#define DDIM 96
#define KDIR 6
#define NST 16
#define RRK 6
#define YSTRIDE 40   // padded row: dt at [0..5], B at [8..23], C at [24..39]
#define NCHUNK 256
#define CHLEN 16     // NCHUNK*CHLEN == L

__device__ __forceinline__ float sigmoidf_(float x) { return 1.f / (1.f + __expf(-x)); }

// scan-position l -> spatial index s for base direction kb in {0,1,2}
__device__ __forceinline__ int sigma_k(int kb, int l) {
    if (kb == 0) return l;
    if (kb == 1) return ((l & 15) << 8) | ((l >> 8) << 4) | ((l >> 4) & 15);
    return (((l >> 4) & 15) << 8) | ((l & 15) << 4) | (l >> 8);
}

// K1: LayerNorm over C + in_proj (192x96). One block per spatial s, 192 threads.
__global__ void k1_ln_inproj(const float* __restrict__ x, const float* __restrict__ ln_w,
                             const float* __restrict__ ln_b, const float* __restrict__ Wp,
                             float* __restrict__ xh_t, float* __restrict__ zs) {
    int s = blockIdx.x;
    int tid = threadIdx.x; // 192
    __shared__ float wsum[4], wsq[4];
    __shared__ __align__(16) float xn[96];
    const float* xr = x + s * CDIM;
    float v = (tid < 96) ? xr[tid] : 0.f;
    float sum = v, sq = v * v;
#pragma unroll
    for (int off = 1; off < 64; off <<= 1) {
        sum += __shfl_xor(sum, off);
        sq  += __shfl_xor(sq, off);
    }
    int wave = tid >> 6, lane = tid & 63;
    if (lane == 0) { wsum[wave] = sum; wsq[wave] = sq; }
    __syncthreads();
    float tot = wsum[0] + wsum[1] + wsum[2];
    float totq = wsq[0] + wsq[1] + wsq[2];
    float mean = tot * (1.f / 96.f);
    float var = totq * (1.f / 96.f) - mean * mean;
    float rstd = rsqrtf(var + 1e-6f);
    if (tid < 96) xn[tid] = (v - mean) * rstd * ln_w[tid] + ln_b[tid];
    __syncthreads();
    const float4* wr = (const float4*)(Wp + tid * 96);
    const float4* xn4 = (const float4*)xn;
    float acc = 0.f;
#pragma unroll
    for (int c4 = 0; c4 < 24; c4++) {
        float4 w4 = wr[c4]; float4 x4 = xn4[c4];
        acc += w4.x * x4.x + w4.y * x4.y + w4.z * x4.z + w4.w * x4.w;
    }
    if (tid < 96) xh_t[tid * L + s] = acc;
    else zs[s * 96 + (tid - 96)] = acc * sigmoidf_(acc);
}

// K2: depthwise 3x3x3 conv (SAME) + bias + SiLU; writes xc[c][s] and xcT[s][c]
__global__ void k2_conv(const float* __restrict__ xh_t, const float* __restrict__ cw,
                        const float* __restrict__ cb, float* __restrict__ xc,
                        float* __restrict__ xcT) {
    int idx = blockIdx.x * 256 + threadIdx.x; // 96*4096
    int c = idx >> 12, s = idx & 4095;
    int dz = s >> 8, h = (s >> 4) & 15, w = s & 15;
    const float* xin = xh_t + c * L;
    const float* wc = cw + c * 27;
    float acc = cb[c];
#pragma unroll
    for (int i = 0; i < 3; i++) {
        int z2 = dz + i - 1; if ((unsigned)z2 > 15u) continue;
#pragma unroll
        for (int j = 0; j < 3; j++) {
            int h2 = h + j - 1; if ((unsigned)h2 > 15u) continue;
#pragma unroll
            for (int kk = 0; kk < 3; kk++) {
                int w2 = w + kk - 1; if ((unsigned)w2 > 15u) continue;
                acc += xin[z2 * 256 + h2 * 16 + w2] * wc[i * 9 + j * 3 + kk];
            }
        }
    }
    float r = acc * sigmoidf_(acc);
    xc[c * L + s] = r;
    xcT[s * 96 + c] = r;
}

// K3: Y2[k][s][YSTRIDE]: dt at [0..5], B at [8..23], C at [24..39]
__global__ void k3_xproj(const float* __restrict__ xc, const float* __restrict__ Wx,
                         float* __restrict__ Y2) {
    int k = blockIdx.x;
    int s = blockIdx.y * 256 + threadIdx.x;
    int ch = blockIdx.z;
    float acc[19];
#pragma unroll
    for (int i = 0; i < 19; i++) acc[i] = 0.f;
    const float* wk = Wx + (k * (RRK + 2 * NST) + ch * 19) * DDIM;
    for (int dd = 0; dd < 96; dd += 4) {
        float v[4];
#pragma unroll
        for (int j = 0; j < 4; j++) v[j] = xc[(dd + j) * L + s];
#pragma unroll
        for (int j = 0; j < 4; j++)
#pragma unroll
            for (int i = 0; i < 19; i++) acc[i] += wk[i * DDIM + dd + j] * v[j];
    }
    float* yo = Y2 + ((size_t)k * L + s) * YSTRIDE;
#pragma unroll
    for (int i = 0; i < 19; i++) {
        int c = ch * 19 + i;
        int off = (c < 6) ? c : (c + 2);
        yo[off] = acc[i];
    }
}

// K4 flat: Zs[k][s][d] = softplus( sum_r Wdt[k][d][r]*Y2[k][s][r] + bdt[k][d] )
__global__ void k4_dt(const float* __restrict__ Y2, const float* __restrict__ Wdt,
                      const float* __restrict__ bdt, float* __restrict__ Zs) {
    int idx = blockIdx.x * 256 + threadIdx.x;   // < 6*4096*96
    int d = idx % 96;
    int rest = idx / 96;
    int s = rest & 4095;
    int k = rest >> 12;
    const float* yr = Y2 + ((size_t)k * L + s) * YSTRIDE;
    const float* wr = Wdt + (k * DDIM + d) * RRK;
    float acc = bdt[k * DDIM + d];
#pragma unroll
    for (int r = 0; r < RRK; r++) acc += wr[r] * yr[r];
    float sp = (acc > 20.f) ? acc : log1pf(__expf(acc));
    Zs[idx] = sp;
}

// ---- 3-phase chunked selective scan, one thread owns all 16 n-states ----
// thread t: d = t%96 (fastest, coalesced), chunk = (t/96)%NCHUNK, k = t/(96*NCHUNK)
// per-chunk state: Aa/Ab/Pb [k][chunk][d][n(16)]

__global__ void __launch_bounds__(256) ka_scan(
        const float* __restrict__ Zs, const float* __restrict__ xcT,
        const float* __restrict__ Y2, const float* __restrict__ A_log,
        float* __restrict__ Aa, float* __restrict__ Ab) {
    int t = blockIdx.x * 256 + threadIdx.x;
    int d = t % 96;
    int rest = t / 96;
    int chunk = rest % NCHUNK;
    int k = rest / NCHUNK;
    int kb = (k < 3) ? k : (k - 3);
    bool flip = (k >= 3);
    float An[16];
    {
        const float4* al4 = (const float4*)(A_log + ((size_t)k * 96 + d) * 16);
        float tmp[16];
        ((float4*)tmp)[0] = al4[0]; ((float4*)tmp)[1] = al4[1];
        ((float4*)tmp)[2] = al4[2]; ((float4*)tmp)[3] = al4[3];
#pragma unroll
        for (int n = 0; n < 16; n++) An[n] = -__expf(tmp[n]);
    }
    float a[16], b[16];
#pragma unroll
    for (int n = 0; n < 16; n++) { a[n] = 1.f; b[n] = 0.f; }
    const float* Zk = Zs + (size_t)k * L * 96;
    const float* Yk = Y2 + (size_t)k * L * YSTRIDE;
    int l0 = chunk * CHLEN;
    int sArr[CHLEN];
#pragma unroll
    for (int i = 0; i < CHLEN; i++) {
        int l = l0 + i;
        int lp = flip ? (4095 - l) : l;
        sArr[i] = sigma_k(kb, lp);
    }
    // software pipeline: load i+1 while computing i
    float dt_c, xv_c, Bv_c[16];
    {
        int s = sArr[0];
        dt_c = Zk[(size_t)s * 96 + d];
        xv_c = xcT[(size_t)s * 96 + d];
        const float4* B4 = (const float4*)(Yk + (size_t)s * YSTRIDE + 8);
        ((float4*)Bv_c)[0] = B4[0]; ((float4*)Bv_c)[1] = B4[1];
        ((float4*)Bv_c)[2] = B4[2]; ((float4*)Bv_c)[3] = B4[3];
    }
#pragma unroll
    for (int i = 0; i < CHLEN; i++) {
        float dt_n, xv_n, Bv_n[16];
        if (i + 1 < CHLEN) {
            int s = sArr[i + 1];
            dt_n = Zk[(size_t)s * 96 + d];
            xv_n = xcT[(size_t)s * 96 + d];
            const float4* B4 = (const float4*)(Yk + (size_t)s * YSTRIDE + 8);
            ((float4*)Bv_n)[0] = B4[0]; ((float4*)Bv_n)[1] = B4[1];
            ((float4*)Bv_n)[2] = B4[2]; ((float4*)Bv_n)[3] = B4[3];
        }
        float dtx = dt_c * xv_c;
#pragma unroll
        for (int n = 0; n < 16; n++) {
            float dA = __expf(dt_c * An[n]);
            b[n] = dA * b[n] + dtx * Bv_c[n];
            a[n] *= dA;
        }
        if (i + 1 < CHLEN) {
            dt_c = dt_n; xv_c = xv_n;
#pragma unroll
            for (int n = 0; n < 16; n++) Bv_c[n] = Bv_n[n];
        }
    }
    size_t o = (((size_t)k * NCHUNK + chunk) * 96 + d) * 16;
    float4* Aa4 = (float4*)(Aa + o);
    float4* Ab4 = (float4*)(Ab + o);
    Aa4[0] = ((float4*)a)[0]; Aa4[1] = ((float4*)a)[1];
    Aa4[2] = ((float4*)a)[2]; Aa4[3] = ((float4*)a)[3];
    Ab4[0] = ((float4*)b)[0]; Ab4[1] = ((float4*)b)[1];
    Ab4[2] = ((float4*)b)[2]; Ab4[3] = ((float4*)b)[3];
}

// Phase B: serial combine across 256 chunks; Pb may alias Aa (read-before-write per batch)
__global__ void __launch_bounds__(256) kb_combine(
        const float* __restrict__ Aa, const float* __restrict__ Ab,
        float* __restrict__ Pb) {
    int t = blockIdx.x * 256 + threadIdx.x;  // < 6*96*16
    int n = t & 15;
    int rest = t >> 4;
    int d = rest % 96;
    int k = rest / 96;
    size_t base = ((size_t)k * NCHUNK * 96 + d) * 16 + n;
    const size_t cstride = 96 * 16;
    float rb = 0.f;
    for (int c0 = 0; c0 < NCHUNK; c0 += 8) {
        float av[8], bv[8];
#pragma unroll
        for (int j = 0; j < 8; j++) {
            av[j] = Aa[base + (size_t)(c0 + j) * cstride];
            bv[j] = Ab[base + (size_t)(c0 + j) * cstride];
        }
#pragma unroll
        for (int j = 0; j < 8; j++) {
            Pb[base + (size_t)(c0 + j) * cstride] = rb;
            rb = av[j] * rb + bv[j];
        }
    }
}

// Phase C: re-scan with carry, fuse y = sum_n h*C + D*x
__global__ void __launch_bounds__(256) kc_apply(
        const float* __restrict__ Zs, const float* __restrict__ xcT,
        const float* __restrict__ Y2, const float* __restrict__ A_log,
        const float* __restrict__ D_skip, const float* __restrict__ Pb,
        float* __restrict__ ys_buf) {
    int t = blockIdx.x * 256 + threadIdx.x;
    int d = t % 96;
    int rest = t / 96;
    int chunk = rest % NCHUNK;
    int k = rest / NCHUNK;
    int kb = (k < 3) ? k : (k - 3);
    bool flip = (k >= 3);
    float An[16];
    {
        const float4* al4 = (const float4*)(A_log + ((size_t)k * 96 + d) * 16);
        float tmp[16];
        ((float4*)tmp)[0] = al4[0]; ((float4*)tmp)[1] = al4[1];
        ((float4*)tmp)[2] = al4[2]; ((float4*)tmp)[3] = al4[3];
#pragma unroll
        for (int n = 0; n < 16; n++) An[n] = -__expf(tmp[n]);
    }
    float Dk = D_skip[k * DDIM + d];
    float h[16];
    {
        const float4* p4 = (const float4*)(Pb + (((size_t)k * NCHUNK + chunk) * 96 + d) * 16);
        ((float4*)h)[0] = p4[0]; ((float4*)h)[1] = p4[1];
        ((float4*)h)[2] = p4[2]; ((float4*)h)[3] = p4[3];
    }
    const float* Zk = Zs + (size_t)k * L * 96;
    const float* Yk = Y2 + (size_t)k * L * YSTRIDE;
    float* ysk = ys_buf + (size_t)k * L * 96;
    int l0 = chunk * CHLEN;
    int sArr[CHLEN];
#pragma unroll
    for (int i = 0; i < CHLEN; i++) {
        int l = l0 + i;
        int lp = flip ? (4095 - l) : l;
        sArr[i] = sigma_k(kb, lp);
    }
    float dt_c, xv_c, Bv_c[16], Cv_c[16];
    {
        int s = sArr[0];
        dt_c = Zk[(size_t)s * 96 + d];
        xv_c = xcT[(size_t)s * 96 + d];
        const float4* B4 = (const float4*)(Yk + (size_t)s * YSTRIDE + 8);
        ((float4*)Bv_c)[0] = B4[0]; ((float4*)Bv_c)[1] = B4[1];
        ((float4*)Bv_c)[2] = B4[2]; ((float4*)Bv_c)[3] = B4[3];
        ((float4*)Cv_c)[0] = B4[4]; ((float4*)Cv_c)[1] = B4[5];
        ((float4*)Cv_c)[2] = B4[6]; ((float4*)Cv_c)[3] = B4[7];
    }
#pragma unroll
    for (int i = 0; i < CHLEN; i++) {
        float dt_n, xv_n, Bv_n[16], Cv_n[16];
        if (i + 1 < CHLEN) {
            int s = sArr[i + 1];
            dt_n = Zk[(size_t)s * 96 + d];
            xv_n = xcT[(size_t)s * 96 + d];
            const float4* B4 = (const float4*)(Yk + (size_t)s * YSTRIDE + 8);
            ((float4*)Bv_n)[0] = B4[0]; ((float4*)Bv_n)[1] = B4[1];
            ((float4*)Bv_n)[2] = B4[2]; ((float4*)Bv_n)[3] = B4[3];
            ((float4*)Cv_n)[0] = B4[4]; ((float4*)Cv_n)[1] = B4[5];
            ((float4*)Cv_n)[2] = B4[6]; ((float4*)Cv_n)[3] = B4[7];
        }
        float dtx = dt_c * xv_c;
        float y = Dk * xv_c;
#pragma unroll
        for (int n = 0; n < 16; n++) {
            float dA = __expf(dt_c * An[n]);
            h[n] = dA * h[n] + dtx * Bv_c[n];
            y += h[n] * Cv_c[n];
        }
        ysk[(size_t)sArr[i] * 96 + d] = y;
        if (i + 1 < CHLEN) {
            dt_c = dt_n; xv_c = xv_n;
#pragma unroll
            for (int n = 0; n < 16; n++) { Bv_c[n] = Bv_n[n]; Cv_c[n] = Cv_n[n]; }
        }
    }
}

// K6: sum 6 dirs + out LayerNorm + gate with silu(z) + out_proj + residual (128 thr)
__global__ void k6_out(const float* __restrict__ ys_buf, const float* __restrict__ zs,
                       const float* __restrict__ onw, const float* __restrict__ onb,
                       const float* __restrict__ Wo, const float* __restrict__ x,
                       float* __restrict__ out) {
    int s = blockIdx.x; int tid = threadIdx.x; // 128
    __shared__ float wsum[2], wsq[2];
    __shared__ __align__(16) float g[96];
    float v = 0.f;
    if (tid < 96) {
#pragma unroll
        for (int k = 0; k < KDIR; k++) v += ys_buf[((size_t)k * L + s) * 96 + tid];
    }
    float sum = v, sq = v * v;
#pragma unroll
    for (int off = 1; off < 64; off <<= 1) {
        sum += __shfl_xor(sum, off);
        sq  += __shfl_xor(sq, off);
    }
    int wave = tid >> 6, lane = tid & 63;
    if (lane == 0) { wsum[wave] = sum; wsq[wave] = sq; }
    __syncthreads();
    float tot = wsum[0] + wsum[1];
    float totq = wsq[0] + wsq[1];
    float mean = tot * (1.f / 96.f);
    float var = totq * (1.f / 96.f) - mean * mean;
    float rstd = rsqrtf(var + 1e-5f);
    if (tid < 96) g[tid] = ((v - mean) * rstd * onw[tid] + onb[tid]) * zs[s * 96 + tid];
    __syncthreads();
    if (tid < 96) {
        const float4* wr = (const float4*)(Wo + tid * 96);
        const float4* g4 = (const float4*)g;
        float acc = x[s * 96 + tid];
#pragma unroll
        for (int c4 = 0; c4 < 24; c4++) {
            float4 w4 = wr[c4]; float4 x4 = g4[c4];
            acc += w4.x * x4.x + w4.y * x4.y + w4.z * x4.z + w4.w * x4.w;
        }
        out[s * 96 + tid] = acc;
    }
}

extern "C" void kernel_launch(void* const* d_in, const int* in_sizes, int n_in,
                              void* d_out, int out_size, void* d_ws, size_t ws_size,
                              hipStream_t stream) {
    const float* x        = (const float*)d_in[0];
    const float* ln1_w    = (const float*)d_in[1];
    const float* ln1_b    = (const float*)d_in[2];
    const float* in_proj  = (const float*)d_in[3];
    const float* conv_w   = (const float*)d_in[4];
    const float* conv_b   = (const float*)d_in[5];
    const float* x_proj   = (const float*)d_in[6];
    const float* dt_w     = (const float*)d_in[7];
    const float* dt_b     = (const float*)d_in[8];
    const float* A_log    = (const float*)d_in[9];
    const float* D_skip   = (const float*)d_in[10];
    const float* onw      = (const float*)d_in[11];
    const float* onb      = (const float*)d_in[12];
    const float* out_w    = (const float*)d_in[13];
    float* out = (float*)d_out;

    float* xh_t = (float*)d_ws;                       // 96*4096
    float* zs   = xh_t + 96 * L;                      // 4096*96
    float* xc   = zs + 96 * L;                        // 96*4096
    float* xcT  = xc + 96 * L;                        // 4096*96
    float* Y2   = xcT + 96 * L;                       // 6*4096*40
    float* Zs   = Y2 + (size_t)KDIR * L * YSTRIDE;    // 6*4096*96
    float* Aa   = Zs + (size_t)KDIR * L * DDIM;       // 6*256*96*16
    float* Ab   = Aa + (size_t)KDIR * NCHUNK * DDIM * NST;
    float* Pb   = Aa;   // alias: kb reads batch before writing
    float* ysb  = Ab;   // alias: Ab dead after kb

    k1_ln_inproj<<<dim3(L), dim3(192), 0, stream>>>(x, ln1_w, ln1_b, in_proj, xh_t, zs);
    k2_conv<<<dim3(96 * L / 256), dim3(256), 0, stream>>>(xh_t, conv_w, conv_b, xc, xcT);
    k3_xproj<<<dim3(KDIR, 16, 2), dim3(256), 0, stream>>>(xc, x_proj, Y2);
    k4_dt<<<dim3(KDIR * L * DDIM / 256), dim3(256), 0, stream>>>(Y2, dt_w, dt_b, Zs);
    ka_scan<<<dim3(KDIR * NCHUNK * DDIM / 256), dim3(256), 0, stream>>>(Zs, xcT, Y2, A_log, Aa, Ab);
    kb_combine<<<dim3(KDIR * DDIM * NST / 256), dim3(256), 0, stream>>>(Aa, Ab, Pb);
    kc_apply<<<dim3(KDIR * NCHUNK * DDIM / 256), dim3(256), 0, stream>>>(Zs, xcT, Y2, A_log, D_skip, Pb, ysb);
    k6_out<<<dim3(L), dim3(128), 0, stream>>>(ysb, zs, onw, onb, out_w, x, out);
}

// Round 5
// 224.204 us; speedup vs baseline: 1.7034x; 1.1878x over previous
//
#include <hip/hip_runtime.h>
#include <hip/hip_bf16.h>

// Sizes (fixed): B=1, D=H=W=16 -> L=4096, C=96, d=96, K=6, N=16, R=6
#define L 4096
#define CDIM 96
#define DDIM 96
#define KDIR 6
#define NST 16
#define RRK 6
#define YSTRIDE 40   // padded row: dt at [0..5], B at [8..23], C at [24..39]
#define NCHUNK 512
#define CHLEN 8      // NCHUNK*CHLEN == L

__device__ __forceinline__ float sigmoidf_(float x) { return 1.f / (1.f + __expf(-x)); }

// scan-position l -> spatial index s for base direction kb in {0,1,2}
__device__ __forceinline__ int sigma_k(int kb, int l) {
    if (kb == 0) return l;
    if (kb == 1) return ((l & 15) << 8) | ((l >> 8) << 4) | ((l >> 4) & 15);
    return (((l >> 4) & 15) << 8) | ((l & 15) << 4) | (l >> 8);
}

// K1: LN + in_proj, weight-in-registers, 8 spatial rows per block.
// grid 512, 192 threads. Outputs xh_t[e][s] (e<96) and zs[s][e-96]=silu.
__global__ void __launch_bounds__(192) k1_ln_inproj(
        const float* __restrict__ x, const float* __restrict__ ln_w,
        const float* __restrict__ ln_b, const float* __restrict__ Wp,
        float* __restrict__ xh_t, float* __restrict__ zs) {
    int s0 = blockIdx.x * 8;
    int tid = threadIdx.x;
    __shared__ __align__(16) float xt[8][96];
    __shared__ __align__(16) float xn[8][96];
    __shared__ float mss[8], rss[8];
    // stage x tile (coalesced float4)
    ((float4*)&xt[0][0])[tid] = ((const float4*)(x + (size_t)s0 * 96))[tid];
    __syncthreads();
    // per-row stats: wave w handles rows w, w+3, w+6
    int wave = tid >> 6, lane = tid & 63;
    for (int r = wave; r < 8; r += 3) {
        float v = xt[r][lane] + ((lane < 32) ? xt[r][64 + lane] : 0.f);
#pragma unroll
        for (int off = 1; off < 64; off <<= 1) v += __shfl_xor(v, off);
        float vs = xt[r][lane] * xt[r][lane] + ((lane < 32) ? xt[r][64 + lane] * xt[r][64 + lane] : 0.f);
#pragma unroll
        for (int off = 1; off < 64; off <<= 1) vs += __shfl_xor(vs, off);
        if (lane == 0) {
            float mean = v * (1.f / 96.f);
            float var = vs * (1.f / 96.f) - mean * mean;
            mss[r] = mean; rss[r] = rsqrtf(var + 1e-6f);
        }
    }
    __syncthreads();
    // normalize: one float4 per thread (192 = 8 rows * 24 quads)
    {
        int r = tid / 24, c4 = tid % 24;
        float4 xv = ((float4*)&xt[r][0])[c4];
        float4 wv = ((const float4*)ln_w)[c4];
        float4 bv = ((const float4*)ln_b)[c4];
        float m = mss[r], rs = rss[r];
        float4 o;
        o.x = (xv.x - m) * rs * wv.x + bv.x;
        o.y = (xv.y - m) * rs * wv.y + bv.y;
        o.z = (xv.z - m) * rs * wv.z + bv.z;
        o.w = (xv.w - m) * rs * wv.w + bv.w;
        ((float4*)&xn[r][0])[c4] = o;
    }
    // load W row into registers (amortized over 8 s-rows)
    float4 Wr[24];
    const float4* wr = (const float4*)(Wp + (size_t)tid * 96);
#pragma unroll
    for (int c4 = 0; c4 < 24; c4++) Wr[c4] = wr[c4];
    __syncthreads();
#pragma unroll
    for (int s = 0; s < 8; s++) {
        const float4* xr4 = (const float4*)&xn[s][0];
        float a0 = 0.f, a1 = 0.f, a2 = 0.f, a3 = 0.f;
#pragma unroll
        for (int c4 = 0; c4 < 24; c4 += 4) {
            float4 x0 = xr4[c4], x1 = xr4[c4 + 1], x2 = xr4[c4 + 2], x3 = xr4[c4 + 3];
            a0 += Wr[c4].x * x0.x + Wr[c4].y * x0.y + Wr[c4].z * x0.z + Wr[c4].w * x0.w;
            a1 += Wr[c4+1].x * x1.x + Wr[c4+1].y * x1.y + Wr[c4+1].z * x1.z + Wr[c4+1].w * x1.w;
            a2 += Wr[c4+2].x * x2.x + Wr[c4+2].y * x2.y + Wr[c4+2].z * x2.z + Wr[c4+2].w * x2.w;
            a3 += Wr[c4+3].x * x3.x + Wr[c4+3].y * x3.y + Wr[c4+3].z * x3.z + Wr[c4+3].w * x3.w;
        }
        float acc = (a0 + a1) + (a2 + a3);
        if (tid < 96) xh_t[(size_t)tid * L + s0 + s] = acc;
        else zs[(size_t)(s0 + s) * 96 + (tid - 96)] = acc * sigmoidf_(acc);
    }
}

// K2: depthwise 3x3x3 conv (SAME) + bias + SiLU; writes xc[c][s] and xcT[s][c]
__global__ void k2_conv(const float* __restrict__ xh_t, const float* __restrict__ cw,
                        const float* __restrict__ cb, float* __restrict__ xc,
                        float* __restrict__ xcT) {
    int idx = blockIdx.x * 256 + threadIdx.x; // 96*4096
    int c = idx >> 12, s = idx & 4095;
    int dz = s >> 8, h = (s >> 4) & 15, w = s & 15;
    const float* xin = xh_t + c * L;
    const float* wc = cw + c * 27;
    float acc = cb[c];
#pragma unroll
    for (int i = 0; i < 3; i++) {
        int z2 = dz + i - 1; if ((unsigned)z2 > 15u) continue;
#pragma unroll
        for (int j = 0; j < 3; j++) {
            int h2 = h + j - 1; if ((unsigned)h2 > 15u) continue;
#pragma unroll
            for (int kk = 0; kk < 3; kk++) {
                int w2 = w + kk - 1; if ((unsigned)w2 > 15u) continue;
                acc += xin[z2 * 256 + h2 * 16 + w2] * wc[i * 9 + j * 3 + kk];
            }
        }
    }
    float r = acc * sigmoidf_(acc);
    xc[c * L + s] = r;
    xcT[s * 96 + c] = r;
}

// K3: Y2[k][s][YSTRIDE]: dt at [0..5], B at [8..23], C at [24..39]
__global__ void k3_xproj(const float* __restrict__ xc, const float* __restrict__ Wx,
                         float* __restrict__ Y2) {
    int k = blockIdx.x;
    int s = blockIdx.y * 256 + threadIdx.x;
    int ch = blockIdx.z;
    float acc[19];
#pragma unroll
    for (int i = 0; i < 19; i++) acc[i] = 0.f;
    const float* wk = Wx + (k * (RRK + 2 * NST) + ch * 19) * DDIM;
    for (int dd = 0; dd < 96; dd += 4) {
        float v[4];
#pragma unroll
        for (int j = 0; j < 4; j++) v[j] = xc[(dd + j) * L + s];
#pragma unroll
        for (int j = 0; j < 4; j++)
#pragma unroll
            for (int i = 0; i < 19; i++) acc[i] += wk[i * DDIM + dd + j] * v[j];
    }
    float* yo = Y2 + ((size_t)k * L + s) * YSTRIDE;
#pragma unroll
    for (int i = 0; i < 19; i++) {
        int c = ch * 19 + i;
        int off = (c < 6) ? c : (c + 2);
        yo[off] = acc[i];
    }
}

// K4 flat: Zs[k][s][d] = softplus( sum_r Wdt[k][d][r]*Y2[k][s][r] + bdt[k][d] )
__global__ void k4_dt(const float* __restrict__ Y2, const float* __restrict__ Wdt,
                      const float* __restrict__ bdt, float* __restrict__ Zs) {
    int idx = blockIdx.x * 256 + threadIdx.x;   // < 6*4096*96
    int d = idx % 96;
    int rest = idx / 96;
    int s = rest & 4095;
    int k = rest >> 12;
    const float* yr = Y2 + ((size_t)k * L + s) * YSTRIDE;
    const float* wr = Wdt + (k * DDIM + d) * RRK;
    float acc = bdt[k * DDIM + d];
#pragma unroll
    for (int r = 0; r < RRK; r++) acc += wr[r] * yr[r];
    float sp = (acc > 15.f) ? acc : __logf(1.f + __expf(acc));
    Zs[idx] = sp;
}

// ---- 3-phase chunked selective scan, one thread owns all 16 n-states ----
// thread t: d = t%96 (coalesced), chunk = (t/96)%NCHUNK, k = t/(96*NCHUNK)

__global__ void __launch_bounds__(256) ka_scan(
        const float* __restrict__ Zs, const float* __restrict__ xcT,
        const float* __restrict__ Y2, const float* __restrict__ A_log,
        float* __restrict__ Aa, float* __restrict__ Ab) {
    int t = blockIdx.x * 256 + threadIdx.x;
    int d = t % 96;
    int rest = t / 96;
    int chunk = rest % NCHUNK;
    int k = rest / NCHUNK;
    int kb = (k < 3) ? k : (k - 3);
    bool flip = (k >= 3);
    float An[16];
    {
        const float4* al4 = (const float4*)(A_log + ((size_t)k * 96 + d) * 16);
        float tmp[16];
        ((float4*)tmp)[0] = al4[0]; ((float4*)tmp)[1] = al4[1];
        ((float4*)tmp)[2] = al4[2]; ((float4*)tmp)[3] = al4[3];
#pragma unroll
        for (int n = 0; n < 16; n++) An[n] = -__expf(tmp[n]);
    }
    float a[16], b[16];
#pragma unroll
    for (int n = 0; n < 16; n++) { a[n] = 1.f; b[n] = 0.f; }
    const float* Zk = Zs + (size_t)k * L * 96;
    const float* Yk = Y2 + (size_t)k * L * YSTRIDE;
    int l0 = chunk * CHLEN;
    int sArr[CHLEN];
#pragma unroll
    for (int i = 0; i < CHLEN; i++) {
        int l = l0 + i;
        int lp = flip ? (4095 - l) : l;
        sArr[i] = sigma_k(kb, lp);
    }
    float dt_c, xv_c, Bv_c[16];
    {
        int s = sArr[0];
        dt_c = Zk[(size_t)s * 96 + d];
        xv_c = xcT[(size_t)s * 96 + d];
        const float4* B4 = (const float4*)(Yk + (size_t)s * YSTRIDE + 8);
        ((float4*)Bv_c)[0] = B4[0]; ((float4*)Bv_c)[1] = B4[1];
        ((float4*)Bv_c)[2] = B4[2]; ((float4*)Bv_c)[3] = B4[3];
    }
#pragma unroll
    for (int i = 0; i < CHLEN; i++) {
        float dt_n, xv_n, Bv_n[16];
        if (i + 1 < CHLEN) {
            int s = sArr[i + 1];
            dt_n = Zk[(size_t)s * 96 + d];
            xv_n = xcT[(size_t)s * 96 + d];
            const float4* B4 = (const float4*)(Yk + (size_t)s * YSTRIDE + 8);
            ((float4*)Bv_n)[0] = B4[0]; ((float4*)Bv_n)[1] = B4[1];
            ((float4*)Bv_n)[2] = B4[2]; ((float4*)Bv_n)[3] = B4[3];
        }
        float dtx = dt_c * xv_c;
#pragma unroll
        for (int n = 0; n < 16; n++) {
            float dA = __expf(dt_c * An[n]);
            b[n] = dA * b[n] + dtx * Bv_c[n];
            a[n] *= dA;
        }
        if (i + 1 < CHLEN) {
            dt_c = dt_n; xv_c = xv_n;
#pragma unroll
            for (int n = 0; n < 16; n++) Bv_c[n] = Bv_n[n];
        }
    }
    size_t o = (((size_t)k * NCHUNK + chunk) * 96 + d) * 16;
    float4* Aa4 = (float4*)(Aa + o);
    float4* Ab4 = (float4*)(Ab + o);
    Aa4[0] = ((float4*)a)[0]; Aa4[1] = ((float4*)a)[1];
    Aa4[2] = ((float4*)a)[2]; Aa4[3] = ((float4*)a)[3];
    Ab4[0] = ((float4*)b)[0]; Ab4[1] = ((float4*)b)[1];
    Ab4[2] = ((float4*)b)[2]; Ab4[3] = ((float4*)b)[3];
}

// Phase B: serial combine across chunks; Pb aliases Aa (read batch before write)
__global__ void __launch_bounds__(256) kb_combine(
        const float* __restrict__ Aa, const float* __restrict__ Ab,
        float* __restrict__ Pb) {
    int t = blockIdx.x * 256 + threadIdx.x;  // < 6*96*16
    int n = t & 15;
    int rest = t >> 4;
    int d = rest % 96;
    int k = rest / 96;
    size_t base = ((size_t)k * NCHUNK * 96 + d) * 16 + n;
    const size_t cstride = 96 * 16;
    float rb = 0.f;
    for (int c0 = 0; c0 < NCHUNK; c0 += 16) {
        float av[16], bv[16];
#pragma unroll
        for (int j = 0; j < 16; j++) {
            av[j] = Aa[base + (size_t)(c0 + j) * cstride];
            bv[j] = Ab[base + (size_t)(c0 + j) * cstride];
        }
#pragma unroll
        for (int j = 0; j < 16; j++) {
            Pb[base + (size_t)(c0 + j) * cstride] = rb;
            rb = av[j] * rb + bv[j];
        }
    }
}

// Phase C: re-scan with carry, fuse y = sum_n h*C + D*x
__global__ void __launch_bounds__(256) kc_apply(
        const float* __restrict__ Zs, const float* __restrict__ xcT,
        const float* __restrict__ Y2, const float* __restrict__ A_log,
        const float* __restrict__ D_skip, const float* __restrict__ Pb,
        float* __restrict__ ys_buf) {
    int t = blockIdx.x * 256 + threadIdx.x;
    int d = t % 96;
    int rest = t / 96;
    int chunk = rest % NCHUNK;
    int k = rest / NCHUNK;
    int kb = (k < 3) ? k : (k - 3);
    bool flip = (k >= 3);
    float An[16];
    {
        const float4* al4 = (const float4*)(A_log + ((size_t)k * 96 + d) * 16);
        float tmp[16];
        ((float4*)tmp)[0] = al4[0]; ((float4*)tmp)[1] = al4[1];
        ((float4*)tmp)[2] = al4[2]; ((float4*)tmp)[3] = al4[3];
#pragma unroll
        for (int n = 0; n < 16; n++) An[n] = -__expf(tmp[n]);
    }
    float Dk = D_skip[k * DDIM + d];
    float h[16];
    {
        const float4* p4 = (const float4*)(Pb + (((size_t)k * NCHUNK + chunk) * 96 + d) * 16);
        ((float4*)h)[0] = p4[0]; ((float4*)h)[1] = p4[1];
        ((float4*)h)[2] = p4[2]; ((float4*)h)[3] = p4[3];
    }
    const float* Zk = Zs + (size_t)k * L * 96;
    const float* Yk = Y2 + (size_t)k * L * YSTRIDE;
    float* ysk = ys_buf + (size_t)k * L * 96;
    int l0 = chunk * CHLEN;
    int sArr[CHLEN];
#pragma unroll
    for (int i = 0; i < CHLEN; i++) {
        int l = l0 + i;
        int lp = flip ? (4095 - l) : l;
        sArr[i] = sigma_k(kb, lp);
    }
    float dt_c, xv_c, Bv_c[16], Cv_c[16];
    {
        int s = sArr[0];
        dt_c = Zk[(size_t)s * 96 + d];
        xv_c = xcT[(size_t)s * 96 + d];
        const float4* B4 = (const float4*)(Yk + (size_t)s * YSTRIDE + 8);
        ((float4*)Bv_c)[0] = B4[0]; ((float4*)Bv_c)[1] = B4[1];
        ((float4*)Bv_c)[2] = B4[2]; ((float4*)Bv_c)[3] = B4[3];
        ((float4*)Cv_c)[0] = B4[4]; ((float4*)Cv_c)[1] = B4[5];
        ((float4*)Cv_c)[2] = B4[6]; ((float4*)Cv_c)[3] = B4[7];
    }
#pragma unroll
    for (int i = 0; i < CHLEN; i++) {
        float dt_n, xv_n, Bv_n[16], Cv_n[16];
        if (i + 1 < CHLEN) {
            int s = sArr[i + 1];
            dt_n = Zk[(size_t)s * 96 + d];
            xv_n = xcT[(size_t)s * 96 + d];
            const float4* B4 = (const float4*)(Yk + (size_t)s * YSTRIDE + 8);
            ((float4*)Bv_n)[0] = B4[0]; ((float4*)Bv_n)[1] = B4[1];
            ((float4*)Bv_n)[2] = B4[2]; ((float4*)Bv_n)[3] = B4[3];
            ((float4*)Cv_n)[0] = B4[4]; ((float4*)Cv_n)[1] = B4[5];
            ((float4*)Cv_n)[2] = B4[6]; ((float4*)Cv_n)[3] = B4[7];
        }
        float dtx = dt_c * xv_c;
        float y = Dk * xv_c;
#pragma unroll
        for (int n = 0; n < 16; n++) {
            float dA = __expf(dt_c * An[n]);
            h[n] = dA * h[n] + dtx * Bv_c[n];
            y += h[n] * Cv_c[n];
        }
        ysk[(size_t)sArr[i] * 96 + d] = y;
        if (i + 1 < CHLEN) {
            dt_c = dt_n; xv_c = xv_n;
#pragma unroll
            for (int n = 0; n < 16; n++) { Bv_c[n] = Bv_n[n]; Cv_c[n] = Cv_n[n]; }
        }
    }
}

// K6: weight-in-registers out stage. grid 256, 192 thr, 16 s-rows per block.
__global__ void __launch_bounds__(192) k6_out(
        const float* __restrict__ ys_buf, const float* __restrict__ zs,
        const float* __restrict__ onw, const float* __restrict__ onb,
        const float* __restrict__ Wo, const float* __restrict__ x,
        float* __restrict__ out) {
    int s0 = blockIdx.x * 16;
    int tid = threadIdx.x;
    __shared__ __align__(16) float vt[16][96];
    __shared__ __align__(16) float gt[16][96];
    __shared__ float mss[16], rss[16];
    // v-tile: 1536 elems / 192 thr = 8 each, coalesced in c
#pragma unroll
    for (int j = 0; j < 8; j++) {
        int f = tid + j * 192;
        int sr = f / 96, c = f % 96;
        float v = 0.f;
#pragma unroll
        for (int k = 0; k < KDIR; k++)
            v += ys_buf[((size_t)k * L + s0 + sr) * 96 + c];
        vt[sr][c] = v;
    }
    __syncthreads();
    int wave = tid >> 6, lane = tid & 63;
    for (int r = wave; r < 16; r += 3) {
        float v = vt[r][lane] + ((lane < 32) ? vt[r][64 + lane] : 0.f);
#pragma unroll
        for (int off = 1; off < 64; off <<= 1) v += __shfl_xor(v, off);
        float vs = vt[r][lane] * vt[r][lane] + ((lane < 32) ? vt[r][64 + lane] * vt[r][64 + lane] : 0.f);
#pragma unroll
        for (int off = 1; off < 64; off <<= 1) vs += __shfl_xor(vs, off);
        if (lane == 0) {
            float mean = v * (1.f / 96.f);
            float var = vs * (1.f / 96.f) - mean * mean;
            mss[r] = mean; rss[r] = rsqrtf(var + 1e-5f);
        }
    }
    __syncthreads();
#pragma unroll
    for (int j = 0; j < 8; j++) {
        int f = tid + j * 192;
        int sr = f / 96, c = f % 96;
        float g = (vt[sr][c] - mss[sr]) * rss[sr] * onw[c] + onb[c];
        gt[sr][c] = g * zs[(size_t)(s0 + sr) * 96 + c];
    }
    // W row in registers
    int e = tid % 96, sg = tid / 96;  // sg in {0,1}
    float4 Wr[24];
    const float4* wr = (const float4*)(Wo + (size_t)e * 96);
#pragma unroll
    for (int c4 = 0; c4 < 24; c4++) Wr[c4] = wr[c4];
    __syncthreads();
#pragma unroll
    for (int j = 0; j < 8; j++) {
        int s = sg * 8 + j;
        const float4* g4 = (const float4*)&gt[s][0];
        float a0 = 0.f, a1 = 0.f, a2 = 0.f, a3 = 0.f;
#pragma unroll
        for (int c4 = 0; c4 < 24; c4 += 4) {
            float4 x0 = g4[c4], x1 = g4[c4 + 1], x2 = g4[c4 + 2], x3 = g4[c4 + 3];
            a0 += Wr[c4].x * x0.x + Wr[c4].y * x0.y + Wr[c4].z * x0.z + Wr[c4].w * x0.w;
            a1 += Wr[c4+1].x * x1.x + Wr[c4+1].y * x1.y + Wr[c4+1].z * x1.z + Wr[c4+1].w * x1.w;
            a2 += Wr[c4+2].x * x2.x + Wr[c4+2].y * x2.y + Wr[c4+2].z * x2.z + Wr[c4+2].w * x2.w;
            a3 += Wr[c4+3].x * x3.x + Wr[c4+3].y * x3.y + Wr[c4+3].z * x3.z + Wr[c4+3].w * x3.w;
        }
        float acc = (a0 + a1) + (a2 + a3) + x[(size_t)(s0 + s) * 96 + e];
        out[(size_t)(s0 + s) * 96 + e] = acc;
    }
}

extern "C" void kernel_launch(void* const* d_in, const int* in_sizes, int n_in,
                              void* d_out, int out_size, void* d_ws, size_t ws_size,
                              hipStream_t stream) {
    const float* x        = (const float*)d_in[0];
    const float* ln1_w    = (const float*)d_in[1];
    const float* ln1_b    = (const float*)d_in[2];
    const float* in_proj  = (const float*)d_in[3];
    const float* conv_w   = (const float*)d_in[4];
    const float* conv_b   = (const float*)d_in[5];
    const float* x_proj   = (const float*)d_in[6];
    const float* dt_w     = (const float*)d_in[7];
    const float* dt_b     = (const float*)d_in[8];
    const float* A_log    = (const float*)d_in[9];
    const float* D_skip   = (const float*)d_in[10];
    const float* onw      = (const float*)d_in[11];
    const float* onb      = (const float*)d_in[12];
    const float* out_w    = (const float*)d_in[13];
    float* out = (float*)d_out;

    float* xh_t = (float*)d_ws;                       // 96*4096
    float* zs   = xh_t + 96 * L;                      // 4096*96
    float* xc   = zs + 96 * L;                        // 96*4096
    float* xcT  = xc + 96 * L;                        // 4096*96
    float* Y2   = xcT + 96 * L;                       // 6*4096*40
    float* Zs   = Y2 + (size_t)KDIR * L * YSTRIDE;    // 6*4096*96
    float* Aa   = Zs + (size_t)KDIR * L * DDIM;       // 6*512*96*16
    float* Ab   = Aa + (size_t)KDIR * NCHUNK * DDIM * NST;
    float* Pb   = Aa;   // alias: kb reads batch before writing
    float* ysb  = Ab;   // alias: Ab dead after kb

    k1_ln_inproj<<<dim3(L / 8), dim3(192), 0, stream>>>(x, ln1_w, ln1_b, in_proj, xh_t, zs);
    k2_conv<<<dim3(96 * L / 256), dim3(256), 0, stream>>>(xh_t, conv_w, conv_b, xc, xcT);
    k3_xproj<<<dim3(KDIR, 16, 2), dim3(256), 0, stream>>>(xc, x_proj, Y2);
    k4_dt<<<dim3(KDIR * L * DDIM / 256), dim3(256), 0, stream>>>(Y2, dt_w, dt_b, Zs);
    ka_scan<<<dim3(KDIR * NCHUNK * DDIM / 256), dim3(256), 0, stream>>>(Zs, xcT, Y2, A_log, Aa, Ab);
    kb_combine<<<dim3(KDIR * DDIM * NST / 256), dim3(256), 0, stream>>>(Aa, Ab, Pb);
    kc_apply<<<dim3(KDIR * NCHUNK * DDIM / 256), dim3(256), 0, stream>>>(Zs, xcT, Y2, A_log, D_skip, Pb, ysb);
    k6_out<<<dim3(L / 16), dim3(192), 0, stream>>>(ysb, zs, onw, onb, out_w, x, out);
}

// Round 6
// 204.148 us; speedup vs baseline: 1.8707x; 1.0982x over previous
//
#include <hip/hip_runtime.h>
#include <hip/hip_bf16.h>

// Sizes (fixed): B=1, D=H=W=16 -> L=4096, C=96, d=96, K=6, N=16, R=6
#define L 4096
#define CDIM 96
#define DDIM 96
#define KDIR 6
#define NST 16
#define RRK 6
#define YSTRIDE 40   // padded row: dt at [0..5], B at [8..23], C at [24..39]
#define NCHUNK 512
#define CHLEN 8      // NCHUNK*CHLEN == L

__device__ __forceinline__ float sigmoidf_(float x) { return 1.f / (1.f + __expf(-x)); }

// scan-position l -> spatial index s for base direction kb in {0,1,2}
__device__ __forceinline__ int sigma_k(int kb, int l) {
    if (kb == 0) return l;
    if (kb == 1) return ((l & 15) << 8) | ((l >> 8) << 4) | ((l >> 4) & 15);
    return (((l >> 4) & 15) << 8) | ((l & 15) << 4) | (l >> 8);
}

// K1: LN + in_proj, weight-in-registers, 8 spatial rows per block.
__global__ void __launch_bounds__(192) k1_ln_inproj(
        const float* __restrict__ x, const float* __restrict__ ln_w,
        const float* __restrict__ ln_b, const float* __restrict__ Wp,
        float* __restrict__ xh_t, float* __restrict__ zs) {
    int s0 = blockIdx.x * 8;
    int tid = threadIdx.x;
    __shared__ __align__(16) float xt[8][96];
    __shared__ __align__(16) float xn[8][96];
    __shared__ float mss[8], rss[8];
    ((float4*)&xt[0][0])[tid] = ((const float4*)(x + (size_t)s0 * 96))[tid];
    __syncthreads();
    int wave = tid >> 6, lane = tid & 63;
    for (int r = wave; r < 8; r += 3) {
        float v = xt[r][lane] + ((lane < 32) ? xt[r][64 + lane] : 0.f);
#pragma unroll
        for (int off = 1; off < 64; off <<= 1) v += __shfl_xor(v, off);
        float vs = xt[r][lane] * xt[r][lane] + ((lane < 32) ? xt[r][64 + lane] * xt[r][64 + lane] : 0.f);
#pragma unroll
        for (int off = 1; off < 64; off <<= 1) vs += __shfl_xor(vs, off);
        if (lane == 0) {
            float mean = v * (1.f / 96.f);
            float var = vs * (1.f / 96.f) - mean * mean;
            mss[r] = mean; rss[r] = rsqrtf(var + 1e-6f);
        }
    }
    __syncthreads();
    {
        int r = tid / 24, c4 = tid % 24;
        float4 xv = ((float4*)&xt[r][0])[c4];
        float4 wv = ((const float4*)ln_w)[c4];
        float4 bv = ((const float4*)ln_b)[c4];
        float m = mss[r], rs = rss[r];
        float4 o;
        o.x = (xv.x - m) * rs * wv.x + bv.x;
        o.y = (xv.y - m) * rs * wv.y + bv.y;
        o.z = (xv.z - m) * rs * wv.z + bv.z;
        o.w = (xv.w - m) * rs * wv.w + bv.w;
        ((float4*)&xn[r][0])[c4] = o;
    }
    float4 Wr[24];
    const float4* wr = (const float4*)(Wp + (size_t)tid * 96);
#pragma unroll
    for (int c4 = 0; c4 < 24; c4++) Wr[c4] = wr[c4];
    __syncthreads();
#pragma unroll
    for (int s = 0; s < 8; s++) {
        const float4* xr4 = (const float4*)&xn[s][0];
        float a0 = 0.f, a1 = 0.f, a2 = 0.f, a3 = 0.f;
#pragma unroll
        for (int c4 = 0; c4 < 24; c4 += 4) {
            float4 x0 = xr4[c4], x1 = xr4[c4 + 1], x2 = xr4[c4 + 2], x3 = xr4[c4 + 3];
            a0 += Wr[c4].x * x0.x + Wr[c4].y * x0.y + Wr[c4].z * x0.z + Wr[c4].w * x0.w;
            a1 += Wr[c4+1].x * x1.x + Wr[c4+1].y * x1.y + Wr[c4+1].z * x1.z + Wr[c4+1].w * x1.w;
            a2 += Wr[c4+2].x * x2.x + Wr[c4+2].y * x2.y + Wr[c4+2].z * x2.z + Wr[c4+2].w * x2.w;
            a3 += Wr[c4+3].x * x3.x + Wr[c4+3].y * x3.y + Wr[c4+3].z * x3.z + Wr[c4+3].w * x3.w;
        }
        float acc = (a0 + a1) + (a2 + a3);
        if (tid < 96) xh_t[(size_t)tid * L + s0 + s] = acc;
        else zs[(size_t)(s0 + s) * 96 + (tid - 96)] = acc * sigmoidf_(acc);
    }
}

// K2: depthwise 3x3x3 conv (SAME) + bias + SiLU; writes xc[c][s] and xcT[s][c]
__global__ void k2_conv(const float* __restrict__ xh_t, const float* __restrict__ cw,
                        const float* __restrict__ cb, float* __restrict__ xc,
                        float* __restrict__ xcT) {
    int idx = blockIdx.x * 256 + threadIdx.x; // 96*4096
    int c = idx >> 12, s = idx & 4095;
    int dz = s >> 8, h = (s >> 4) & 15, w = s & 15;
    const float* xin = xh_t + c * L;
    const float* wc = cw + c * 27;
    float acc = cb[c];
#pragma unroll
    for (int i = 0; i < 3; i++) {
        int z2 = dz + i - 1; if ((unsigned)z2 > 15u) continue;
#pragma unroll
        for (int j = 0; j < 3; j++) {
            int h2 = h + j - 1; if ((unsigned)h2 > 15u) continue;
#pragma unroll
            for (int kk = 0; kk < 3; kk++) {
                int w2 = w + kk - 1; if ((unsigned)w2 > 15u) continue;
                acc += xin[z2 * 256 + h2 * 16 + w2] * wc[i * 9 + j * 3 + kk];
            }
        }
    }
    float r = acc * sigmoidf_(acc);
    xc[c * L + s] = r;
    xcT[s * 96 + c] = r;
}

// K3: Y2[k][s][YSTRIDE]: dt at [0..5], B at [8..23], C at [24..39]
// grid (6, 16, 4): 4 channel groups of 10/10/9/9
__global__ void k3_xproj(const float* __restrict__ xc, const float* __restrict__ Wx,
                         float* __restrict__ Y2) {
    int k = blockIdx.x;
    int s = blockIdx.y * 256 + threadIdx.x;
    int ch = blockIdx.z;
    int base = (ch < 2) ? ch * 10 : 20 + (ch - 2) * 9;
    int cnt = (ch < 2) ? 10 : 9;
    float acc[10];
#pragma unroll
    for (int i = 0; i < 10; i++) acc[i] = 0.f;
    const float* wk = Wx + ((size_t)k * (RRK + 2 * NST) + base) * DDIM;
    for (int dd = 0; dd < 96; dd += 4) {
        float v[4];
#pragma unroll
        for (int j = 0; j < 4; j++) v[j] = xc[(dd + j) * L + s];
#pragma unroll
        for (int j = 0; j < 4; j++)
#pragma unroll
            for (int i = 0; i < 10; i++) acc[i] += wk[i * DDIM + dd + j] * v[j];
    }
    float* yo = Y2 + ((size_t)k * L + s) * YSTRIDE;
#pragma unroll
    for (int i = 0; i < 10; i++) {
        if (i < cnt) {
            int c = base + i;
            int off = (c < 6) ? c : (c + 2);
            yo[off] = acc[i];
        }
    }
}

// K4 flat: Zs[k][s][d] = softplus( sum_r Wdt[k][d][r]*Y2[k][s][r] + bdt[k][d] )
__global__ void k4_dt(const float* __restrict__ Y2, const float* __restrict__ Wdt,
                      const float* __restrict__ bdt, float* __restrict__ Zs) {
    int idx = blockIdx.x * 256 + threadIdx.x;   // < 6*4096*96
    int d = idx % 96;
    int rest = idx / 96;
    int s = rest & 4095;
    int k = rest >> 12;
    const float* yr = Y2 + ((size_t)k * L + s) * YSTRIDE;
    const float* wr = Wdt + (k * DDIM + d) * RRK;
    float acc = bdt[k * DDIM + d];
#pragma unroll
    for (int r = 0; r < RRK; r++) acc += wr[r] * yr[r];
    float sp = (acc > 15.f) ? acc : __logf(1.f + __expf(acc));
    Zs[idx] = sp;
}

// ---- 3-phase chunked scan, n-split: thread owns 8 of 16 states ----
// thread t: nh = t&1, d = (t>>1)%96, chunk = ((t>>1)/96)%NCHUNK, k = (t>>1)/(96*NCHUNK)
// state layout (kb-compatible): [k][chunk][d][16]

__global__ void __launch_bounds__(256) ka_scan(
        const float* __restrict__ Zs, const float* __restrict__ xcT,
        const float* __restrict__ Y2, const float* __restrict__ A_log,
        float* __restrict__ Aa, float* __restrict__ Ab) {
    int t = blockIdx.x * 256 + threadIdx.x;
    int nh = t & 1;
    int q = t >> 1;
    int d = q % 96;
    int rest = q / 96;
    int chunk = rest % NCHUNK;
    int k = rest / NCHUNK;
    int kb = (k < 3) ? k : (k - 3);
    bool flip = (k >= 3);
    float An[8];
    {
        const float4* al4 = (const float4*)(A_log + ((size_t)k * 96 + d) * 16 + nh * 8);
        float tmp[8];
        ((float4*)tmp)[0] = al4[0]; ((float4*)tmp)[1] = al4[1];
#pragma unroll
        for (int n = 0; n < 8; n++) An[n] = -__expf(tmp[n]);
    }
    float a[8], b[8];
#pragma unroll
    for (int n = 0; n < 8; n++) { a[n] = 1.f; b[n] = 0.f; }
    const float* Zk = Zs + (size_t)k * L * 96;
    const float* Yk = Y2 + (size_t)k * L * YSTRIDE;
    int l0 = chunk * CHLEN;
    int sArr[CHLEN];
#pragma unroll
    for (int i = 0; i < CHLEN; i++) {
        int l = l0 + i;
        int lp = flip ? (4095 - l) : l;
        sArr[i] = sigma_k(kb, lp);
    }
    float dt_c, xv_c, Bv_c[8];
    {
        int s = sArr[0];
        dt_c = Zk[(size_t)s * 96 + d];
        xv_c = xcT[(size_t)s * 96 + d];
        const float4* B4 = (const float4*)(Yk + (size_t)s * YSTRIDE + 8 + nh * 8);
        ((float4*)Bv_c)[0] = B4[0]; ((float4*)Bv_c)[1] = B4[1];
    }
#pragma unroll
    for (int i = 0; i < CHLEN; i++) {
        float dt_n, xv_n, Bv_n[8];
        if (i + 1 < CHLEN) {
            int s = sArr[i + 1];
            dt_n = Zk[(size_t)s * 96 + d];
            xv_n = xcT[(size_t)s * 96 + d];
            const float4* B4 = (const float4*)(Yk + (size_t)s * YSTRIDE + 8 + nh * 8);
            ((float4*)Bv_n)[0] = B4[0]; ((float4*)Bv_n)[1] = B4[1];
        }
        float dtx = dt_c * xv_c;
#pragma unroll
        for (int n = 0; n < 8; n++) {
            float dA = __expf(dt_c * An[n]);
            b[n] = dA * b[n] + dtx * Bv_c[n];
            a[n] *= dA;
        }
        if (i + 1 < CHLEN) {
            dt_c = dt_n; xv_c = xv_n;
#pragma unroll
            for (int n = 0; n < 8; n++) Bv_c[n] = Bv_n[n];
        }
    }
    size_t o = (((size_t)k * NCHUNK + chunk) * 96 + d) * 16 + nh * 8;
    float4* Aa4 = (float4*)(Aa + o);
    float4* Ab4 = (float4*)(Ab + o);
    Aa4[0] = ((float4*)a)[0]; Aa4[1] = ((float4*)a)[1];
    Ab4[0] = ((float4*)b)[0]; Ab4[1] = ((float4*)b)[1];
}

// Phase B: serial combine across chunks; Pb aliases Aa (read batch before write)
__global__ void __launch_bounds__(256) kb_combine(
        const float* __restrict__ Aa, const float* __restrict__ Ab,
        float* __restrict__ Pb) {
    int t = blockIdx.x * 256 + threadIdx.x;  // < 6*96*16
    int n = t & 15;
    int rest = t >> 4;
    int d = rest % 96;
    int k = rest / 96;
    size_t base = ((size_t)k * NCHUNK * 96 + d) * 16 + n;
    const size_t cstride = 96 * 16;
    float rb = 0.f;
    for (int c0 = 0; c0 < NCHUNK; c0 += 16) {
        float av[16], bv[16];
#pragma unroll
        for (int j = 0; j < 16; j++) {
            av[j] = Aa[base + (size_t)(c0 + j) * cstride];
            bv[j] = Ab[base + (size_t)(c0 + j) * cstride];
        }
#pragma unroll
        for (int j = 0; j < 16; j++) {
            Pb[base + (size_t)(c0 + j) * cstride] = rb;
            rb = av[j] * rb + bv[j];
        }
    }
}

// Phase C: re-scan with carry, fuse y = sum_n h*C + D*x  (n-split + pair reduce)
__global__ void __launch_bounds__(256) kc_apply(
        const float* __restrict__ Zs, const float* __restrict__ xcT,
        const float* __restrict__ Y2, const float* __restrict__ A_log,
        const float* __restrict__ D_skip, const float* __restrict__ Pb,
        float* __restrict__ ys_buf) {
    int t = blockIdx.x * 256 + threadIdx.x;
    int nh = t & 1;
    int q = t >> 1;
    int d = q % 96;
    int rest = q / 96;
    int chunk = rest % NCHUNK;
    int k = rest / NCHUNK;
    int kb = (k < 3) ? k : (k - 3);
    bool flip = (k >= 3);
    float An[8];
    {
        const float4* al4 = (const float4*)(A_log + ((size_t)k * 96 + d) * 16 + nh * 8);
        float tmp[8];
        ((float4*)tmp)[0] = al4[0]; ((float4*)tmp)[1] = al4[1];
#pragma unroll
        for (int n = 0; n < 8; n++) An[n] = -__expf(tmp[n]);
    }
    float Dk = D_skip[k * DDIM + d];
    float h[8];
    {
        const float4* p4 = (const float4*)(Pb + (((size_t)k * NCHUNK + chunk) * 96 + d) * 16 + nh * 8);
        ((float4*)h)[0] = p4[0]; ((float4*)h)[1] = p4[1];
    }
    const float* Zk = Zs + (size_t)k * L * 96;
    const float* Yk = Y2 + (size_t)k * L * YSTRIDE;
    float* ysk = ys_buf + (size_t)k * L * 96;
    int l0 = chunk * CHLEN;
    int sArr[CHLEN];
#pragma unroll
    for (int i = 0; i < CHLEN; i++) {
        int l = l0 + i;
        int lp = flip ? (4095 - l) : l;
        sArr[i] = sigma_k(kb, lp);
    }
    float dt_c, xv_c, Bv_c[8], Cv_c[8];
    {
        int s = sArr[0];
        dt_c = Zk[(size_t)s * 96 + d];
        xv_c = xcT[(size_t)s * 96 + d];
        const float4* B4 = (const float4*)(Yk + (size_t)s * YSTRIDE + 8 + nh * 8);
        ((float4*)Bv_c)[0] = B4[0]; ((float4*)Bv_c)[1] = B4[1];
        ((float4*)Cv_c)[0] = B4[4]; ((float4*)Cv_c)[1] = B4[5];
    }
#pragma unroll
    for (int i = 0; i < CHLEN; i++) {
        float dt_n, xv_n, Bv_n[8], Cv_n[8];
        if (i + 1 < CHLEN) {
            int s = sArr[i + 1];
            dt_n = Zk[(size_t)s * 96 + d];
            xv_n = xcT[(size_t)s * 96 + d];
            const float4* B4 = (const float4*)(Yk + (size_t)s * YSTRIDE + 8 + nh * 8);
            ((float4*)Bv_n)[0] = B4[0]; ((float4*)Bv_n)[1] = B4[1];
            ((float4*)Cv_n)[0] = B4[4]; ((float4*)Cv_n)[1] = B4[5];
        }
        float dtx = dt_c * xv_c;
        float p = 0.f;
#pragma unroll
        for (int n = 0; n < 8; n++) {
            float dA = __expf(dt_c * An[n]);
            h[n] = dA * h[n] + dtx * Bv_c[n];
            p += h[n] * Cv_c[n];
        }
        p += __shfl_xor(p, 1);   // combine the two n-halves
        if (nh == 0) ysk[(size_t)sArr[i] * 96 + d] = p + Dk * xv_c;
        if (i + 1 < CHLEN) {
            dt_c = dt_n; xv_c = xv_n;
#pragma unroll
            for (int n = 0; n < 8; n++) { Bv_c[n] = Bv_n[n]; Cv_c[n] = Cv_n[n]; }
        }
    }
}

// K6: weight-in-registers out stage. 16 s-rows per block, 192 thr.
__global__ void __launch_bounds__(192) k6_out(
        const float* __restrict__ ys_buf, const float* __restrict__ zs,
        const float* __restrict__ onw, const float* __restrict__ onb,
        const float* __restrict__ Wo, const float* __restrict__ x,
        float* __restrict__ out) {
    int s0 = blockIdx.x * 16;
    int tid = threadIdx.x;
    __shared__ __align__(16) float vt[16][96];
    __shared__ __align__(16) float gt[16][96];
    __shared__ float mss[16], rss[16];
#pragma unroll
    for (int j = 0; j < 8; j++) {
        int f = tid + j * 192;
        int sr = f / 96, c = f % 96;
        float v = 0.f;
#pragma unroll
        for (int k = 0; k < KDIR; k++)
            v += ys_buf[((size_t)k * L + s0 + sr) * 96 + c];
        vt[sr][c] = v;
    }
    __syncthreads();
    int wave = tid >> 6, lane = tid & 63;
    for (int r = wave; r < 16; r += 3) {
        float v = vt[r][lane] + ((lane < 32) ? vt[r][64 + lane] : 0.f);
#pragma unroll
        for (int off = 1; off < 64; off <<= 1) v += __shfl_xor(v, off);
        float vs = vt[r][lane] * vt[r][lane] + ((lane < 32) ? vt[r][64 + lane] * vt[r][64 + lane] : 0.f);
#pragma unroll
        for (int off = 1; off < 64; off <<= 1) vs += __shfl_xor(vs, off);
        if (lane == 0) {
            float mean = v * (1.f / 96.f);
            float var = vs * (1.f / 96.f) - mean * mean;
            mss[r] = mean; rss[r] = rsqrtf(var + 1e-5f);
        }
    }
    __syncthreads();
#pragma unroll
    for (int j = 0; j < 8; j++) {
        int f = tid + j * 192;
        int sr = f / 96, c = f % 96;
        float g = (vt[sr][c] - mss[sr]) * rss[sr] * onw[c] + onb[c];
        gt[sr][c] = g * zs[(size_t)(s0 + sr) * 96 + c];
    }
    int e = tid % 96, sg = tid / 96;  // sg in {0,1}
    float4 Wr[24];
    const float4* wr = (const float4*)(Wo + (size_t)e * 96);
#pragma unroll
    for (int c4 = 0; c4 < 24; c4++) Wr[c4] = wr[c4];
    __syncthreads();
#pragma unroll
    for (int j = 0; j < 8; j++) {
        int s = sg * 8 + j;
        const float4* g4 = (const float4*)&gt[s][0];
        float a0 = 0.f, a1 = 0.f, a2 = 0.f, a3 = 0.f;
#pragma unroll
        for (int c4 = 0; c4 < 24; c4 += 4) {
            float4 x0 = g4[c4], x1 = g4[c4 + 1], x2 = g4[c4 + 2], x3 = g4[c4 + 3];
            a0 += Wr[c4].x * x0.x + Wr[c4].y * x0.y + Wr[c4].z * x0.z + Wr[c4].w * x0.w;
            a1 += Wr[c4+1].x * x1.x + Wr[c4+1].y * x1.y + Wr[c4+1].z * x1.z + Wr[c4+1].w * x1.w;
            a2 += Wr[c4+2].x * x2.x + Wr[c4+2].y * x2.y + Wr[c4+2].z * x2.z + Wr[c4+2].w * x2.w;
            a3 += Wr[c4+3].x * x3.x + Wr[c4+3].y * x3.y + Wr[c4+3].z * x3.z + Wr[c4+3].w * x3.w;
        }
        float acc = (a0 + a1) + (a2 + a3) + x[(size_t)(s0 + s) * 96 + e];
        out[(size_t)(s0 + s) * 96 + e] = acc;
    }
}

extern "C" void kernel_launch(void* const* d_in, const int* in_sizes, int n_in,
                              void* d_out, int out_size, void* d_ws, size_t ws_size,
                              hipStream_t stream) {
    const float* x        = (const float*)d_in[0];
    const float* ln1_w    = (const float*)d_in[1];
    const float* ln1_b    = (const float*)d_in[2];
    const float* in_proj  = (const float*)d_in[3];
    const float* conv_w   = (const float*)d_in[4];
    const float* conv_b   = (const float*)d_in[5];
    const float* x_proj   = (const float*)d_in[6];
    const float* dt_w     = (const float*)d_in[7];
    const float* dt_b     = (const float*)d_in[8];
    const float* A_log    = (const float*)d_in[9];
    const float* D_skip   = (const float*)d_in[10];
    const float* onw      = (const float*)d_in[11];
    const float* onb      = (const float*)d_in[12];
    const float* out_w    = (const float*)d_in[13];
    float* out = (float*)d_out;

    float* xh_t = (float*)d_ws;                       // 96*4096
    float* zs   = xh_t + 96 * L;                      // 4096*96
    float* xc   = zs + 96 * L;                        // 96*4096
    float* xcT  = xc + 96 * L;                        // 4096*96
    float* Y2   = xcT + 96 * L;                       // 6*4096*40
    float* Zs   = Y2 + (size_t)KDIR * L * YSTRIDE;    // 6*4096*96
    float* Aa   = Zs + (size_t)KDIR * L * DDIM;       // 6*512*96*16
    float* Ab   = Aa + (size_t)KDIR * NCHUNK * DDIM * NST;
    float* Pb   = Aa;   // alias: kb reads batch before writing
    float* ysb  = Ab;   // alias: Ab dead after kb

    k1_ln_inproj<<<dim3(L / 8), dim3(192), 0, stream>>>(x, ln1_w, ln1_b, in_proj, xh_t, zs);
    k2_conv<<<dim3(96 * L / 256), dim3(256), 0, stream>>>(xh_t, conv_w, conv_b, xc, xcT);
    k3_xproj<<<dim3(KDIR, 16, 4), dim3(256), 0, stream>>>(xc, x_proj, Y2);
    k4_dt<<<dim3(KDIR * L * DDIM / 256), dim3(256), 0, stream>>>(Y2, dt_w, dt_b, Zs);
    ka_scan<<<dim3(KDIR * NCHUNK * DDIM * 2 / 256), dim3(256), 0, stream>>>(Zs, xcT, Y2, A_log, Aa, Ab);
    kb_combine<<<dim3(KDIR * DDIM * NST / 256), dim3(256), 0, stream>>>(Aa, Ab, Pb);
    kc_apply<<<dim3(KDIR * NCHUNK * DDIM * 2 / 256), dim3(256), 0, stream>>>(Zs, xcT, Y2, A_log, D_skip, Pb, ysb);
    k6_out<<<dim3(L / 16), dim3(192), 0, stream>>>(ysb, zs, onw, onb, out_w, x, out);
}

// Round 7
// 194.664 us; speedup vs baseline: 1.9619x; 1.0487x over previous
//
#include <hip/hip_runtime.h>
#include <hip/hip_bf16.h>

// Sizes (fixed): B=1, D=H=W=16 -> L=4096, C=96, d=96, K=6, N=16, R=6
#define L 4096
#define CDIM 96
#define DDIM 96
#define KDIR 6
#define NST 16
#define RRK 6
#define YSTRIDE 40   // padded row: B at [8..23], C at [24..39] (dt slots unused)
#define NCHUNK 256
#define CHLEN 16     // NCHUNK*CHLEN == L

typedef _Float16 half4v __attribute__((ext_vector_type(4)));

__device__ __forceinline__ float sigmoidf_(float x) { return 1.f / (1.f + __expf(-x)); }

// scan-position l -> spatial index s for base direction kb in {0,1,2}
__device__ __forceinline__ int sigma_k(int kb, int l) {
    if (kb == 0) return l;
    if (kb == 1) return ((l & 15) << 8) | ((l >> 8) << 4) | ((l >> 4) & 15);
    return (((l >> 4) & 15) << 8) | ((l & 15) << 4) | (l >> 8);
}

// K1: LN + in_proj, weight-in-registers, 8 spatial rows per block.
__global__ void __launch_bounds__(192) k1_ln_inproj(
        const float* __restrict__ x, const float* __restrict__ ln_w,
        const float* __restrict__ ln_b, const float* __restrict__ Wp,
        float* __restrict__ xh_t, float* __restrict__ zs) {
    int s0 = blockIdx.x * 8;
    int tid = threadIdx.x;
    __shared__ __align__(16) float xt[8][96];
    __shared__ __align__(16) float xn[8][96];
    __shared__ float mss[8], rss[8];
    ((float4*)&xt[0][0])[tid] = ((const float4*)(x + (size_t)s0 * 96))[tid];
    __syncthreads();
    int wave = tid >> 6, lane = tid & 63;
    for (int r = wave; r < 8; r += 3) {
        float v = xt[r][lane] + ((lane < 32) ? xt[r][64 + lane] : 0.f);
#pragma unroll
        for (int off = 1; off < 64; off <<= 1) v += __shfl_xor(v, off);
        float vs = xt[r][lane] * xt[r][lane] + ((lane < 32) ? xt[r][64 + lane] * xt[r][64 + lane] : 0.f);
#pragma unroll
        for (int off = 1; off < 64; off <<= 1) vs += __shfl_xor(vs, off);
        if (lane == 0) {
            float mean = v * (1.f / 96.f);
            float var = vs * (1.f / 96.f) - mean * mean;
            mss[r] = mean; rss[r] = rsqrtf(var + 1e-6f);
        }
    }
    __syncthreads();
    {
        int r = tid / 24, c4 = tid % 24;
        float4 xv = ((float4*)&xt[r][0])[c4];
        float4 wv = ((const float4*)ln_w)[c4];
        float4 bv = ((const float4*)ln_b)[c4];
        float m = mss[r], rs = rss[r];
        float4 o;
        o.x = (xv.x - m) * rs * wv.x + bv.x;
        o.y = (xv.y - m) * rs * wv.y + bv.y;
        o.z = (xv.z - m) * rs * wv.z + bv.z;
        o.w = (xv.w - m) * rs * wv.w + bv.w;
        ((float4*)&xn[r][0])[c4] = o;
    }
    float4 Wr[24];
    const float4* wr = (const float4*)(Wp + (size_t)tid * 96);
#pragma unroll
    for (int c4 = 0; c4 < 24; c4++) Wr[c4] = wr[c4];
    __syncthreads();
#pragma unroll
    for (int s = 0; s < 8; s++) {
        const float4* xr4 = (const float4*)&xn[s][0];
        float a0 = 0.f, a1 = 0.f, a2 = 0.f, a3 = 0.f;
#pragma unroll
        for (int c4 = 0; c4 < 24; c4 += 4) {
            float4 x0 = xr4[c4], x1 = xr4[c4 + 1], x2 = xr4[c4 + 2], x3 = xr4[c4 + 3];
            a0 += Wr[c4].x * x0.x + Wr[c4].y * x0.y + Wr[c4].z * x0.z + Wr[c4].w * x0.w;
            a1 += Wr[c4+1].x * x1.x + Wr[c4+1].y * x1.y + Wr[c4+1].z * x1.z + Wr[c4+1].w * x1.w;
            a2 += Wr[c4+2].x * x2.x + Wr[c4+2].y * x2.y + Wr[c4+2].z * x2.z + Wr[c4+2].w * x2.w;
            a3 += Wr[c4+3].x * x3.x + Wr[c4+3].y * x3.y + Wr[c4+3].z * x3.z + Wr[c4+3].w * x3.w;
        }
        float acc = (a0 + a1) + (a2 + a3);
        if (tid < 96) xh_t[(size_t)tid * L + s0 + s] = acc;
        else zs[(size_t)(s0 + s) * 96 + (tid - 96)] = acc * sigmoidf_(acc);
    }
}

// K2: depthwise 3x3x3 conv (SAME) + bias + SiLU; writes xc[c][s] and xcT[s][c]
__global__ void k2_conv(const float* __restrict__ xh_t, const float* __restrict__ cw,
                        const float* __restrict__ cb, float* __restrict__ xc,
                        float* __restrict__ xcT) {
    int idx = blockIdx.x * 256 + threadIdx.x; // 96*4096
    int c = idx >> 12, s = idx & 4095;
    int dz = s >> 8, h = (s >> 4) & 15, w = s & 15;
    const float* xin = xh_t + c * L;
    const float* wc = cw + c * 27;
    float acc = cb[c];
#pragma unroll
    for (int i = 0; i < 3; i++) {
        int z2 = dz + i - 1; if ((unsigned)z2 > 15u) continue;
#pragma unroll
        for (int j = 0; j < 3; j++) {
            int h2 = h + j - 1; if ((unsigned)h2 > 15u) continue;
#pragma unroll
            for (int kk = 0; kk < 3; kk++) {
                int w2 = w + kk - 1; if ((unsigned)w2 > 15u) continue;
                acc += xin[z2 * 256 + h2 * 16 + w2] * wc[i * 9 + j * 3 + kk];
            }
        }
    }
    float r = acc * sigmoidf_(acc);
    xc[c * L + s] = r;
    xcT[s * 96 + c] = r;
}

// K3 (+fused K4): Y2 B/C channels; ch==0 blocks also expand dt -> Zs (softplus)
// grid (6, 16, 4): channel groups of 10/10/9/9 over the 38 projection channels
__global__ void k3_xproj(const float* __restrict__ xc, const float* __restrict__ Wx,
                         const float* __restrict__ Wdt, const float* __restrict__ bdt,
                         float* __restrict__ Y2, float* __restrict__ Zs) {
    int k = blockIdx.x;
    int tid = threadIdx.x;
    int sbase = blockIdx.y * 256;
    int s = sbase + tid;
    int ch = blockIdx.z;
    int base = (ch < 2) ? ch * 10 : 20 + (ch - 2) * 9;
    int cnt = (ch < 2) ? 10 : 9;
    __shared__ float dts[256][6];
    float acc[10];
#pragma unroll
    for (int i = 0; i < 10; i++) acc[i] = 0.f;
    const float* wk = Wx + ((size_t)k * (RRK + 2 * NST) + base) * DDIM;
    for (int dd = 0; dd < 96; dd += 4) {
        float v[4];
#pragma unroll
        for (int j = 0; j < 4; j++) v[j] = xc[(dd + j) * L + s];
#pragma unroll
        for (int j = 0; j < 4; j++)
#pragma unroll
            for (int i = 0; i < 10; i++) acc[i] += wk[i * DDIM + dd + j] * v[j];
    }
    float* yo = Y2 + ((size_t)k * L + s) * YSTRIDE;
#pragma unroll
    for (int i = 0; i < 10; i++) {
        if (i < cnt) {
            int c = base + i;
            if (c >= 6) yo[c + 2] = acc[i];
        }
    }
    if (ch == 0) {
#pragma unroll
        for (int r = 0; r < 6; r++) dts[tid][r] = acc[r];
        __syncthreads();
        // expand: Zs[k][sbase+sr][d] = softplus(bdt + sum_r Wdt[k][d][r]*dt[sr][r])
        for (int i = 0; i < 96; i++) {
            int idx = i * 256 + tid;       // < 24576 = 256 s * 96 d
            int d = idx % 96;
            int sr = idx / 96;
            const float* wr = Wdt + ((size_t)k * 96 + d) * 6;
            float a = bdt[k * 96 + d];
#pragma unroll
            for (int r = 0; r < 6; r++) a += wr[r] * dts[sr][r];
            float sp = (a > 15.f) ? a : __logf(1.f + __expf(a));
            Zs[((size_t)k * L + sbase + sr) * 96 + d] = sp;
        }
    }
}

// ---- 3-phase chunked scan, 4 states/thread (nq = t&3), fp16 chunk state ----
// thread t: nq = t&3, d = (t>>2)%96, chunk = ((t>>2)/96)%NCHUNK, k = (t>>2)/(96*NCHUNK)
// state layout: [k][chunk][d][16]  (half)

__global__ void __launch_bounds__(256) ka_scan(
        const float* __restrict__ Zs, const float* __restrict__ xcT,
        const float* __restrict__ Y2, const float* __restrict__ A_log,
        _Float16* __restrict__ Aah, _Float16* __restrict__ Abh) {
    int t = blockIdx.x * 256 + threadIdx.x;
    int nq = t & 3;
    int q = t >> 2;
    int d = q % 96;
    int rest = q / 96;
    int chunk = rest % NCHUNK;
    int k = rest / NCHUNK;
    int kb = (k < 3) ? k : (k - 3);
    bool flip = (k >= 3);
    float An[4];
    {
        float4 al = *(const float4*)(A_log + ((size_t)k * 96 + d) * 16 + nq * 4);
        An[0] = -__expf(al.x); An[1] = -__expf(al.y);
        An[2] = -__expf(al.z); An[3] = -__expf(al.w);
    }
    float a[4] = {1.f, 1.f, 1.f, 1.f};
    float b[4] = {0.f, 0.f, 0.f, 0.f};
    const float* Zk = Zs + (size_t)k * L * 96;
    const float* Yk = Y2 + (size_t)k * L * YSTRIDE;
    int l0 = chunk * CHLEN;
    for (int i = 0; i < CHLEN; i += 4) {
        int sI[4]; float dt[4], xv[4]; float4 Bv[4];
#pragma unroll
        for (int j = 0; j < 4; j++) {
            int l = l0 + i + j;
            int lp = flip ? (4095 - l) : l;
            sI[j] = sigma_k(kb, lp);
        }
#pragma unroll
        for (int j = 0; j < 4; j++) {
            dt[j] = Zk[(size_t)sI[j] * 96 + d];
            xv[j] = xcT[(size_t)sI[j] * 96 + d];
            Bv[j] = *(const float4*)(Yk + (size_t)sI[j] * YSTRIDE + 8 + nq * 4);
        }
#pragma unroll
        for (int j = 0; j < 4; j++) {
            float dtx = dt[j] * xv[j];
            float e0 = __expf(dt[j] * An[0]);
            float e1 = __expf(dt[j] * An[1]);
            float e2 = __expf(dt[j] * An[2]);
            float e3 = __expf(dt[j] * An[3]);
            b[0] = e0 * b[0] + dtx * Bv[j].x; a[0] *= e0;
            b[1] = e1 * b[1] + dtx * Bv[j].y; a[1] *= e1;
            b[2] = e2 * b[2] + dtx * Bv[j].z; a[2] *= e2;
            b[3] = e3 * b[3] + dtx * Bv[j].w; a[3] *= e3;
        }
    }
    size_t o = (((size_t)k * NCHUNK + chunk) * 96 + d) * 16 + nq * 4;
    half4v ha, hb;
    ha.x = (_Float16)a[0]; ha.y = (_Float16)a[1]; ha.z = (_Float16)a[2]; ha.w = (_Float16)a[3];
    hb.x = (_Float16)b[0]; hb.y = (_Float16)b[1]; hb.z = (_Float16)b[2]; hb.w = (_Float16)b[3];
    *(half4v*)(Aah + o) = ha;
    *(half4v*)(Abh + o) = hb;
}

// Phase B: serial combine across 256 chunks per (k,d,n); fp16 in/out
__global__ void __launch_bounds__(256) kb_combine(
        const _Float16* __restrict__ Aah, const _Float16* __restrict__ Abh,
        _Float16* __restrict__ Pbh) {
    int t = blockIdx.x * 256 + threadIdx.x;  // < 6*96*16 = 9216
    int n = t & 15;
    int rest = t >> 4;
    int d = rest % 96;
    int k = rest / 96;
    size_t base = ((size_t)k * NCHUNK * 96 + d) * 16 + n;
    const size_t cstride = 96 * 16;
    float rb = 0.f;
    for (int c0 = 0; c0 < NCHUNK; c0 += 16) {
        float av[16], bv[16];
#pragma unroll
        for (int j = 0; j < 16; j++) {
            av[j] = (float)Aah[base + (size_t)(c0 + j) * cstride];
            bv[j] = (float)Abh[base + (size_t)(c0 + j) * cstride];
        }
#pragma unroll
        for (int j = 0; j < 16; j++) {
            Pbh[base + (size_t)(c0 + j) * cstride] = (_Float16)rb;
            rb = av[j] * rb + bv[j];
        }
    }
}

// Phase C: re-scan with carry, fuse y = sum_n h*C + D*x  (4-state + 2 shfl hops)
__global__ void __launch_bounds__(256) kc_apply(
        const float* __restrict__ Zs, const float* __restrict__ xcT,
        const float* __restrict__ Y2, const float* __restrict__ A_log,
        const float* __restrict__ D_skip, const _Float16* __restrict__ Pbh,
        float* __restrict__ ys_buf) {
    int t = blockIdx.x * 256 + threadIdx.x;
    int nq = t & 3;
    int q = t >> 2;
    int d = q % 96;
    int rest = q / 96;
    int chunk = rest % NCHUNK;
    int k = rest / NCHUNK;
    int kb = (k < 3) ? k : (k - 3);
    bool flip = (k >= 3);
    float An[4];
    {
        float4 al = *(const float4*)(A_log + ((size_t)k * 96 + d) * 16 + nq * 4);
        An[0] = -__expf(al.x); An[1] = -__expf(al.y);
        An[2] = -__expf(al.z); An[3] = -__expf(al.w);
    }
    float Dk = D_skip[k * DDIM + d];
    float h[4];
    {
        half4v hp = *(const half4v*)(Pbh + (((size_t)k * NCHUNK + chunk) * 96 + d) * 16 + nq * 4);
        h[0] = (float)hp.x; h[1] = (float)hp.y; h[2] = (float)hp.z; h[3] = (float)hp.w;
    }
    const float* Zk = Zs + (size_t)k * L * 96;
    const float* Yk = Y2 + (size_t)k * L * YSTRIDE;
    float* ysk = ys_buf + (size_t)k * L * 96;
    int l0 = chunk * CHLEN;
    for (int i = 0; i < CHLEN; i += 4) {
        int sI[4]; float dt[4], xv[4]; float4 Bv[4], Cv[4];
#pragma unroll
        for (int j = 0; j < 4; j++) {
            int l = l0 + i + j;
            int lp = flip ? (4095 - l) : l;
            sI[j] = sigma_k(kb, lp);
        }
#pragma unroll
        for (int j = 0; j < 4; j++) {
            dt[j] = Zk[(size_t)sI[j] * 96 + d];
            xv[j] = xcT[(size_t)sI[j] * 96 + d];
            Bv[j] = *(const float4*)(Yk + (size_t)sI[j] * YSTRIDE + 8 + nq * 4);
            Cv[j] = *(const float4*)(Yk + (size_t)sI[j] * YSTRIDE + 24 + nq * 4);
        }
#pragma unroll
        for (int j = 0; j < 4; j++) {
            float dtx = dt[j] * xv[j];
            float e0 = __expf(dt[j] * An[0]);
            float e1 = __expf(dt[j] * An[1]);
            float e2 = __expf(dt[j] * An[2]);
            float e3 = __expf(dt[j] * An[3]);
            h[0] = e0 * h[0] + dtx * Bv[j].x;
            h[1] = e1 * h[1] + dtx * Bv[j].y;
            h[2] = e2 * h[2] + dtx * Bv[j].z;
            h[3] = e3 * h[3] + dtx * Bv[j].w;
            float p = h[0] * Cv[j].x + h[1] * Cv[j].y + h[2] * Cv[j].z + h[3] * Cv[j].w;
            p += __shfl_xor(p, 1);
            p += __shfl_xor(p, 2);
            if (nq == 0) ysk[(size_t)sI[j] * 96 + d] = p + Dk * xv[j];
        }
    }
}

// K6: weight-in-registers out stage. 16 s-rows per block, 192 thr.
__global__ void __launch_bounds__(192) k6_out(
        const float* __restrict__ ys_buf, const float* __restrict__ zs,
        const float* __restrict__ onw, const float* __restrict__ onb,
        const float* __restrict__ Wo, const float* __restrict__ x,
        float* __restrict__ out) {
    int s0 = blockIdx.x * 16;
    int tid = threadIdx.x;
    __shared__ __align__(16) float vt[16][96];
    __shared__ __align__(16) float gt[16][96];
    __shared__ float mss[16], rss[16];
#pragma unroll
    for (int j = 0; j < 8; j++) {
        int f = tid + j * 192;
        int sr = f / 96, c = f % 96;
        float v = 0.f;
#pragma unroll
        for (int k = 0; k < KDIR; k++)
            v += ys_buf[((size_t)k * L + s0 + sr) * 96 + c];
        vt[sr][c] = v;
    }
    __syncthreads();
    int wave = tid >> 6, lane = tid & 63;
    for (int r = wave; r < 16; r += 3) {
        float v = vt[r][lane] + ((lane < 32) ? vt[r][64 + lane] : 0.f);
#pragma unroll
        for (int off = 1; off < 64; off <<= 1) v += __shfl_xor(v, off);
        float vs = vt[r][lane] * vt[r][lane] + ((lane < 32) ? vt[r][64 + lane] * vt[r][64 + lane] : 0.f);
#pragma unroll
        for (int off = 1; off < 64; off <<= 1) vs += __shfl_xor(vs, off);
        if (lane == 0) {
            float mean = v * (1.f / 96.f);
            float var = vs * (1.f / 96.f) - mean * mean;
            mss[r] = mean; rss[r] = rsqrtf(var + 1e-5f);
        }
    }
    __syncthreads();
#pragma unroll
    for (int j = 0; j < 8; j++) {
        int f = tid + j * 192;
        int sr = f / 96, c = f % 96;
        float g = (vt[sr][c] - mss[sr]) * rss[sr] * onw[c] + onb[c];
        gt[sr][c] = g * zs[(size_t)(s0 + sr) * 96 + c];
    }
    int e = tid % 96, sg = tid / 96;  // sg in {0,1}
    float4 Wr[24];
    const float4* wr = (const float4*)(Wo + (size_t)e * 96);
#pragma unroll
    for (int c4 = 0; c4 < 24; c4++) Wr[c4] = wr[c4];
    __syncthreads();
#pragma unroll
    for (int j = 0; j < 8; j++) {
        int s = sg * 8 + j;
        const float4* g4 = (const float4*)&gt[s][0];
        float a0 = 0.f, a1 = 0.f, a2 = 0.f, a3 = 0.f;
#pragma unroll
        for (int c4 = 0; c4 < 24; c4 += 4) {
            float4 x0 = g4[c4], x1 = g4[c4 + 1], x2 = g4[c4 + 2], x3 = g4[c4 + 3];
            a0 += Wr[c4].x * x0.x + Wr[c4].y * x0.y + Wr[c4].z * x0.z + Wr[c4].w * x0.w;
            a1 += Wr[c4+1].x * x1.x + Wr[c4+1].y * x1.y + Wr[c4+1].z * x1.z + Wr[c4+1].w * x1.w;
            a2 += Wr[c4+2].x * x2.x + Wr[c4+2].y * x2.y + Wr[c4+2].z * x2.z + Wr[c4+2].w * x2.w;
            a3 += Wr[c4+3].x * x3.x + Wr[c4+3].y * x3.y + Wr[c4+3].z * x3.z + Wr[c4+3].w * x3.w;
        }
        float acc = (a0 + a1) + (a2 + a3) + x[(size_t)(s0 + s) * 96 + e];
        out[(size_t)(s0 + s) * 96 + e] = acc;
    }
}

extern "C" void kernel_launch(void* const* d_in, const int* in_sizes, int n_in,
                              void* d_out, int out_size, void* d_ws, size_t ws_size,
                              hipStream_t stream) {
    const float* x        = (const float*)d_in[0];
    const float* ln1_w    = (const float*)d_in[1];
    const float* ln1_b    = (const float*)d_in[2];
    const float* in_proj  = (const float*)d_in[3];
    const float* conv_w   = (const float*)d_in[4];
    const float* conv_b   = (const float*)d_in[5];
    const float* x_proj   = (const float*)d_in[6];
    const float* dt_w     = (const float*)d_in[7];
    const float* dt_b     = (const float*)d_in[8];
    const float* A_log    = (const float*)d_in[9];
    const float* D_skip   = (const float*)d_in[10];
    const float* onw      = (const float*)d_in[11];
    const float* onb      = (const float*)d_in[12];
    const float* out_w    = (const float*)d_in[13];
    float* out = (float*)d_out;

    float* xh_t = (float*)d_ws;                       // 96*4096
    float* zs   = xh_t + 96 * L;                      // 4096*96
    float* xc   = zs + 96 * L;                        // 96*4096
    float* xcT  = xc + 96 * L;                        // 4096*96
    float* Y2   = xcT + 96 * L;                       // 6*4096*40
    float* Zs   = Y2 + (size_t)KDIR * L * YSTRIDE;    // 6*4096*96
    float* ysb  = Zs + (size_t)KDIR * L * DDIM;       // 6*4096*96
    _Float16* Aah = (_Float16*)(ysb + (size_t)KDIR * L * DDIM);  // 6*256*96*16 halves
    _Float16* Abh = Aah + (size_t)KDIR * NCHUNK * DDIM * NST;
    _Float16* Pbh = Abh + (size_t)KDIR * NCHUNK * DDIM * NST;

    k1_ln_inproj<<<dim3(L / 8), dim3(192), 0, stream>>>(x, ln1_w, ln1_b, in_proj, xh_t, zs);
    k2_conv<<<dim3(96 * L / 256), dim3(256), 0, stream>>>(xh_t, conv_w, conv_b, xc, xcT);
    k3_xproj<<<dim3(KDIR, 16, 4), dim3(256), 0, stream>>>(xc, x_proj, dt_w, dt_b, Y2, Zs);
    ka_scan<<<dim3(KDIR * NCHUNK * DDIM * 4 / 256), dim3(256), 0, stream>>>(Zs, xcT, Y2, A_log, Aah, Abh);
    kb_combine<<<dim3(KDIR * DDIM * NST / 256), dim3(256), 0, stream>>>(Aah, Abh, Pbh);
    kc_apply<<<dim3(KDIR * NCHUNK * DDIM * 4 / 256), dim3(256), 0, stream>>>(Zs, xcT, Y2, A_log, D_skip, Pbh, ysb);
    k6_out<<<dim3(L / 16), dim3(192), 0, stream>>>(ysb, zs, onw, onb, out_w, x, out);
}

// Round 8
// 189.929 us; speedup vs baseline: 2.0108x; 1.0249x over previous
//
#include <hip/hip_runtime.h>
#include <hip/hip_bf16.h>

// Sizes (fixed): B=1, D=H=W=16 -> L=4096, C=96, d=96, K=6, N=16, R=6
#define L 4096
#define CDIM 96
#define DDIM 96
#define KDIR 6
#define NST 16
#define RRK 6
#define YH 32        // Y2h row: B at [0..15], C at [16..31] (half)
#define NCHUNK 256
#define CHLEN 16     // NCHUNK*CHLEN == L

typedef _Float16 half4v __attribute__((ext_vector_type(4)));

__device__ __forceinline__ float sigmoidf_(float x) { return 1.f / (1.f + __expf(-x)); }

// scan-position l -> spatial index s for base direction kb in {0,1,2}
__device__ __forceinline__ int sigma_k(int kb, int l) {
    if (kb == 0) return l;
    if (kb == 1) return ((l & 15) << 8) | ((l >> 8) << 4) | ((l >> 4) & 15);
    return (((l >> 4) & 15) << 8) | ((l & 15) << 4) | (l >> 8);
}

// K1: LN + in_proj, weight-in-registers, 8 spatial rows per block.
__global__ void __launch_bounds__(192) k1_ln_inproj(
        const float* __restrict__ x, const float* __restrict__ ln_w,
        const float* __restrict__ ln_b, const float* __restrict__ Wp,
        _Float16* __restrict__ xhh, _Float16* __restrict__ zsh) {
    int s0 = blockIdx.x * 8;
    int tid = threadIdx.x;
    __shared__ __align__(16) float xt[8][96];
    __shared__ __align__(16) float xn[8][96];
    __shared__ float mss[8], rss[8];
    ((float4*)&xt[0][0])[tid] = ((const float4*)(x + (size_t)s0 * 96))[tid];
    __syncthreads();
    int wave = tid >> 6, lane = tid & 63;
    for (int r = wave; r < 8; r += 3) {
        float v = xt[r][lane] + ((lane < 32) ? xt[r][64 + lane] : 0.f);
#pragma unroll
        for (int off = 1; off < 64; off <<= 1) v += __shfl_xor(v, off);
        float vs = xt[r][lane] * xt[r][lane] + ((lane < 32) ? xt[r][64 + lane] * xt[r][64 + lane] : 0.f);
#pragma unroll
        for (int off = 1; off < 64; off <<= 1) vs += __shfl_xor(vs, off);
        if (lane == 0) {
            float mean = v * (1.f / 96.f);
            float var = vs * (1.f / 96.f) - mean * mean;
            mss[r] = mean; rss[r] = rsqrtf(var + 1e-6f);
        }
    }
    __syncthreads();
    {
        int r = tid / 24, c4 = tid % 24;
        float4 xv = ((float4*)&xt[r][0])[c4];
        float4 wv = ((const float4*)ln_w)[c4];
        float4 bv = ((const float4*)ln_b)[c4];
        float m = mss[r], rs = rss[r];
        float4 o;
        o.x = (xv.x - m) * rs * wv.x + bv.x;
        o.y = (xv.y - m) * rs * wv.y + bv.y;
        o.z = (xv.z - m) * rs * wv.z + bv.z;
        o.w = (xv.w - m) * rs * wv.w + bv.w;
        ((float4*)&xn[r][0])[c4] = o;
    }
    float4 Wr[24];
    const float4* wr = (const float4*)(Wp + (size_t)tid * 96);
#pragma unroll
    for (int c4 = 0; c4 < 24; c4++) Wr[c4] = wr[c4];
    __syncthreads();
#pragma unroll
    for (int s = 0; s < 8; s++) {
        const float4* xr4 = (const float4*)&xn[s][0];
        float a0 = 0.f, a1 = 0.f, a2 = 0.f, a3 = 0.f;
#pragma unroll
        for (int c4 = 0; c4 < 24; c4 += 4) {
            float4 x0 = xr4[c4], x1 = xr4[c4 + 1], x2 = xr4[c4 + 2], x3 = xr4[c4 + 3];
            a0 += Wr[c4].x * x0.x + Wr[c4].y * x0.y + Wr[c4].z * x0.z + Wr[c4].w * x0.w;
            a1 += Wr[c4+1].x * x1.x + Wr[c4+1].y * x1.y + Wr[c4+1].z * x1.z + Wr[c4+1].w * x1.w;
            a2 += Wr[c4+2].x * x2.x + Wr[c4+2].y * x2.y + Wr[c4+2].z * x2.z + Wr[c4+2].w * x2.w;
            a3 += Wr[c4+3].x * x3.x + Wr[c4+3].y * x3.y + Wr[c4+3].z * x3.z + Wr[c4+3].w * x3.w;
        }
        float acc = (a0 + a1) + (a2 + a3);
        if (tid < 96) xhh[(size_t)tid * L + s0 + s] = (_Float16)acc;
        else zsh[(size_t)(s0 + s) * 96 + (tid - 96)] = (_Float16)(acc * sigmoidf_(acc));
    }
}

// K2: depthwise 3x3x3 conv (SAME) + bias + SiLU; writes xch[c][s] and xcTh[s][c]
__global__ void k2_conv(const _Float16* __restrict__ xhh, const float* __restrict__ cw,
                        const float* __restrict__ cb, _Float16* __restrict__ xch,
                        _Float16* __restrict__ xcTh) {
    int idx = blockIdx.x * 256 + threadIdx.x; // 96*4096
    int c = idx >> 12, s = idx & 4095;
    int dz = s >> 8, h = (s >> 4) & 15, w = s & 15;
    const _Float16* xin = xhh + (size_t)c * L;
    const float* wc = cw + c * 27;
    float acc = cb[c];
#pragma unroll
    for (int i = 0; i < 3; i++) {
        int z2 = dz + i - 1; if ((unsigned)z2 > 15u) continue;
#pragma unroll
        for (int j = 0; j < 3; j++) {
            int h2 = h + j - 1; if ((unsigned)h2 > 15u) continue;
#pragma unroll
            for (int kk = 0; kk < 3; kk++) {
                int w2 = w + kk - 1; if ((unsigned)w2 > 15u) continue;
                acc += (float)xin[z2 * 256 + h2 * 16 + w2] * wc[i * 9 + j * 3 + kk];
            }
        }
    }
    float r = acc * sigmoidf_(acc);
    _Float16 hr = (_Float16)r;
    xch[(size_t)c * L + s] = hr;
    xcTh[(size_t)s * 96 + c] = hr;
}

// K3 (+fused K4): Y2h B/C channels (half); ch==0 blocks also expand dt -> Zsh (softplus)
// grid (6, 16, 4): channel groups of 10/10/9/9 over the 38 projection channels
__global__ void k3_xproj(const _Float16* __restrict__ xch, const float* __restrict__ Wx,
                         const float* __restrict__ Wdt, const float* __restrict__ bdt,
                         _Float16* __restrict__ Y2h, _Float16* __restrict__ Zsh) {
    int k = blockIdx.x;
    int tid = threadIdx.x;
    int sbase = blockIdx.y * 256;
    int s = sbase + tid;
    int ch = blockIdx.z;
    int base = (ch < 2) ? ch * 10 : 20 + (ch - 2) * 9;
    int cnt = (ch < 2) ? 10 : 9;
    __shared__ float dts[256][6];
    float acc[10];
#pragma unroll
    for (int i = 0; i < 10; i++) acc[i] = 0.f;
    const float* wk = Wx + ((size_t)k * (RRK + 2 * NST) + base) * DDIM;
    for (int dd = 0; dd < 96; dd += 4) {
        float v[4];
#pragma unroll
        for (int j = 0; j < 4; j++) v[j] = (float)xch[(size_t)(dd + j) * L + s];
#pragma unroll
        for (int j = 0; j < 4; j++)
#pragma unroll
            for (int i = 0; i < 10; i++) acc[i] += wk[i * DDIM + dd + j] * v[j];
    }
    _Float16* yo = Y2h + ((size_t)k * L + s) * YH;
#pragma unroll
    for (int i = 0; i < 10; i++) {
        if (i < cnt) {
            int c = base + i;
            if (c >= 6) yo[c - 6] = (_Float16)acc[i];
        }
    }
    if (ch == 0) {
#pragma unroll
        for (int r = 0; r < 6; r++) dts[tid][r] = acc[r];
        __syncthreads();
        // expand: Zsh[k][sbase+sr][d] = softplus(bdt + sum_r Wdt[k][d][r]*dt[sr][r])
        for (int i = 0; i < 96; i++) {
            int idx = i * 256 + tid;       // < 24576 = 256 s * 96 d
            int d = idx % 96;
            int sr = idx / 96;
            const float* wr = Wdt + ((size_t)k * 96 + d) * 6;
            float a = bdt[k * 96 + d];
#pragma unroll
            for (int r = 0; r < 6; r++) a += wr[r] * dts[sr][r];
            float sp = (a > 15.f) ? a : __logf(1.f + __expf(a));
            Zsh[((size_t)k * L + sbase + sr) * 96 + d] = (_Float16)sp;
        }
    }
}

// ---- 3-phase chunked scan, 4 states/thread (nq = t&3), fp16 everywhere ----
// thread t: nq = t&3, d = (t>>2)%96, chunk = ((t>>2)/96)%NCHUNK, k = (t>>2)/(96*NCHUNK)

__global__ void __launch_bounds__(256) ka_scan(
        const _Float16* __restrict__ Zsh, const _Float16* __restrict__ xcTh,
        const _Float16* __restrict__ Y2h, const float* __restrict__ A_log,
        _Float16* __restrict__ Aah, _Float16* __restrict__ Abh) {
    int t = blockIdx.x * 256 + threadIdx.x;
    int nq = t & 3;
    int q = t >> 2;
    int d = q % 96;
    int rest = q / 96;
    int chunk = rest % NCHUNK;
    int k = rest / NCHUNK;
    int kb = (k < 3) ? k : (k - 3);
    bool flip = (k >= 3);
    float An[4];
    {
        float4 al = *(const float4*)(A_log + ((size_t)k * 96 + d) * 16 + nq * 4);
        An[0] = -__expf(al.x); An[1] = -__expf(al.y);
        An[2] = -__expf(al.z); An[3] = -__expf(al.w);
    }
    float a[4] = {1.f, 1.f, 1.f, 1.f};
    float b[4] = {0.f, 0.f, 0.f, 0.f};
    const _Float16* Zk = Zsh + (size_t)k * L * 96;
    const _Float16* Yk = Y2h + (size_t)k * L * YH;
    int l0 = chunk * CHLEN;
    for (int i = 0; i < CHLEN; i += 4) {
        int sI[4]; float dt[4], xv[4]; half4v Bh[4];
#pragma unroll
        for (int j = 0; j < 4; j++) {
            int l = l0 + i + j;
            int lp = flip ? (4095 - l) : l;
            sI[j] = sigma_k(kb, lp);
        }
#pragma unroll
        for (int j = 0; j < 4; j++) {
            dt[j] = (float)Zk[(size_t)sI[j] * 96 + d];
            xv[j] = (float)xcTh[(size_t)sI[j] * 96 + d];
            Bh[j] = *(const half4v*)(Yk + (size_t)sI[j] * YH + nq * 4);
        }
#pragma unroll
        for (int j = 0; j < 4; j++) {
            float dtx = dt[j] * xv[j];
            float e0 = __expf(dt[j] * An[0]);
            float e1 = __expf(dt[j] * An[1]);
            float e2 = __expf(dt[j] * An[2]);
            float e3 = __expf(dt[j] * An[3]);
            b[0] = e0 * b[0] + dtx * (float)Bh[j].x; a[0] *= e0;
            b[1] = e1 * b[1] + dtx * (float)Bh[j].y; a[1] *= e1;
            b[2] = e2 * b[2] + dtx * (float)Bh[j].z; a[2] *= e2;
            b[3] = e3 * b[3] + dtx * (float)Bh[j].w; a[3] *= e3;
        }
    }
    size_t o = (((size_t)k * NCHUNK + chunk) * 96 + d) * 16 + nq * 4;
    half4v ha, hb;
    ha.x = (_Float16)a[0]; ha.y = (_Float16)a[1]; ha.z = (_Float16)a[2]; ha.w = (_Float16)a[3];
    hb.x = (_Float16)b[0]; hb.y = (_Float16)b[1]; hb.z = (_Float16)b[2]; hb.w = (_Float16)b[3];
    *(half4v*)(Aah + o) = ha;
    *(half4v*)(Abh + o) = hb;
}

// Phase B: serial combine across 256 chunks per (k,d,n); fp16 in/out
__global__ void __launch_bounds__(256) kb_combine(
        const _Float16* __restrict__ Aah, const _Float16* __restrict__ Abh,
        _Float16* __restrict__ Pbh) {
    int t = blockIdx.x * 256 + threadIdx.x;  // < 6*96*16 = 9216
    int n = t & 15;
    int rest = t >> 4;
    int d = rest % 96;
    int k = rest / 96;
    size_t base = ((size_t)k * NCHUNK * 96 + d) * 16 + n;
    const size_t cstride = 96 * 16;
    float rb = 0.f;
    for (int c0 = 0; c0 < NCHUNK; c0 += 16) {
        float av[16], bv[16];
#pragma unroll
        for (int j = 0; j < 16; j++) {
            av[j] = (float)Aah[base + (size_t)(c0 + j) * cstride];
            bv[j] = (float)Abh[base + (size_t)(c0 + j) * cstride];
        }
#pragma unroll
        for (int j = 0; j < 16; j++) {
            Pbh[base + (size_t)(c0 + j) * cstride] = (_Float16)rb;
            rb = av[j] * rb + bv[j];
        }
    }
}

// Phase C: re-scan with carry, fuse y = sum_n h*C + D*x; ysh layout [s][k][d] (half)
__global__ void __launch_bounds__(256) kc_apply(
        const _Float16* __restrict__ Zsh, const _Float16* __restrict__ xcTh,
        const _Float16* __restrict__ Y2h, const float* __restrict__ A_log,
        const float* __restrict__ D_skip, const _Float16* __restrict__ Pbh,
        _Float16* __restrict__ ysh) {
    int t = blockIdx.x * 256 + threadIdx.x;
    int nq = t & 3;
    int q = t >> 2;
    int d = q % 96;
    int rest = q / 96;
    int chunk = rest % NCHUNK;
    int k = rest / NCHUNK;
    int kb = (k < 3) ? k : (k - 3);
    bool flip = (k >= 3);
    float An[4];
    {
        float4 al = *(const float4*)(A_log + ((size_t)k * 96 + d) * 16 + nq * 4);
        An[0] = -__expf(al.x); An[1] = -__expf(al.y);
        An[2] = -__expf(al.z); An[3] = -__expf(al.w);
    }
    float Dk = D_skip[k * DDIM + d];
    float h[4];
    {
        half4v hp = *(const half4v*)(Pbh + (((size_t)k * NCHUNK + chunk) * 96 + d) * 16 + nq * 4);
        h[0] = (float)hp.x; h[1] = (float)hp.y; h[2] = (float)hp.z; h[3] = (float)hp.w;
    }
    const _Float16* Zk = Zsh + (size_t)k * L * 96;
    const _Float16* Yk = Y2h + (size_t)k * L * YH;
    int l0 = chunk * CHLEN;
    for (int i = 0; i < CHLEN; i += 4) {
        int sI[4]; float dt[4], xv[4]; half4v Bh[4], Ch[4];
#pragma unroll
        for (int j = 0; j < 4; j++) {
            int l = l0 + i + j;
            int lp = flip ? (4095 - l) : l;
            sI[j] = sigma_k(kb, lp);
        }
#pragma unroll
        for (int j = 0; j < 4; j++) {
            dt[j] = (float)Zk[(size_t)sI[j] * 96 + d];
            xv[j] = (float)xcTh[(size_t)sI[j] * 96 + d];
            Bh[j] = *(const half4v*)(Yk + (size_t)sI[j] * YH + nq * 4);
            Ch[j] = *(const half4v*)(Yk + (size_t)sI[j] * YH + 16 + nq * 4);
        }
#pragma unroll
        for (int j = 0; j < 4; j++) {
            float dtx = dt[j] * xv[j];
            float e0 = __expf(dt[j] * An[0]);
            float e1 = __expf(dt[j] * An[1]);
            float e2 = __expf(dt[j] * An[2]);
            float e3 = __expf(dt[j] * An[3]);
            h[0] = e0 * h[0] + dtx * (float)Bh[j].x;
            h[1] = e1 * h[1] + dtx * (float)Bh[j].y;
            h[2] = e2 * h[2] + dtx * (float)Bh[j].z;
            h[3] = e3 * h[3] + dtx * (float)Bh[j].w;
            float p = h[0] * (float)Ch[j].x + h[1] * (float)Ch[j].y
                    + h[2] * (float)Ch[j].z + h[3] * (float)Ch[j].w;
            p += __shfl_xor(p, 1);
            p += __shfl_xor(p, 2);
            if (nq == 0) ysh[((size_t)sI[j] * KDIR + k) * 96 + d] = (_Float16)(p + Dk * xv[j]);
        }
    }
}

// K6: weight-in-registers out stage. 8 s-rows per block, 192 thr, grid 512.
__global__ void __launch_bounds__(192) k6_out(
        const _Float16* __restrict__ ysh, const _Float16* __restrict__ zsh,
        const float* __restrict__ onw, const float* __restrict__ onb,
        const float* __restrict__ Wo, const float* __restrict__ x,
        float* __restrict__ out) {
    int s0 = blockIdx.x * 8;
    int tid = threadIdx.x;
    __shared__ __align__(16) float vt[8][96];
    __shared__ __align__(16) float gt[8][96];
    __shared__ float mss[8], rss[8];
#pragma unroll
    for (int j = 0; j < 4; j++) {
        int f = tid + j * 192;           // < 768
        int sr = f / 96, c = f % 96;
        const _Float16* yr = ysh + ((size_t)(s0 + sr) * KDIR) * 96 + c;
        float v = 0.f;
#pragma unroll
        for (int k = 0; k < KDIR; k++) v += (float)yr[k * 96];
        vt[sr][c] = v;
    }
    __syncthreads();
    int wave = tid >> 6, lane = tid & 63;
    for (int r = wave; r < 8; r += 3) {
        float v = vt[r][lane] + ((lane < 32) ? vt[r][64 + lane] : 0.f);
#pragma unroll
        for (int off = 1; off < 64; off <<= 1) v += __shfl_xor(v, off);
        float vs = vt[r][lane] * vt[r][lane] + ((lane < 32) ? vt[r][64 + lane] * vt[r][64 + lane] : 0.f);
#pragma unroll
        for (int off = 1; off < 64; off <<= 1) vs += __shfl_xor(vs, off);
        if (lane == 0) {
            float mean = v * (1.f / 96.f);
            float var = vs * (1.f / 96.f) - mean * mean;
            mss[r] = mean; rss[r] = rsqrtf(var + 1e-5f);
        }
    }
    __syncthreads();
#pragma unroll
    for (int j = 0; j < 4; j++) {
        int f = tid + j * 192;
        int sr = f / 96, c = f % 96;
        float g = (vt[sr][c] - mss[sr]) * rss[sr] * onw[c] + onb[c];
        gt[sr][c] = g * (float)zsh[(size_t)(s0 + sr) * 96 + c];
    }
    int e = tid % 96, sg = tid / 96;  // sg in {0,1}
    float4 Wr[24];
    const float4* wr = (const float4*)(Wo + (size_t)e * 96);
#pragma unroll
    for (int c4 = 0; c4 < 24; c4++) Wr[c4] = wr[c4];
    __syncthreads();
#pragma unroll
    for (int j = 0; j < 4; j++) {
        int s = sg * 4 + j;
        const float4* g4 = (const float4*)&gt[s][0];
        float a0 = 0.f, a1 = 0.f, a2 = 0.f, a3 = 0.f;
#pragma unroll
        for (int c4 = 0; c4 < 24; c4 += 4) {
            float4 x0 = g4[c4], x1 = g4[c4 + 1], x2 = g4[c4 + 2], x3 = g4[c4 + 3];
            a0 += Wr[c4].x * x0.x + Wr[c4].y * x0.y + Wr[c4].z * x0.z + Wr[c4].w * x0.w;
            a1 += Wr[c4+1].x * x1.x + Wr[c4+1].y * x1.y + Wr[c4+1].z * x1.z + Wr[c4+1].w * x1.w;
            a2 += Wr[c4+2].x * x2.x + Wr[c4+2].y * x2.y + Wr[c4+2].z * x2.z + Wr[c4+2].w * x2.w;
            a3 += Wr[c4+3].x * x3.x + Wr[c4+3].y * x3.y + Wr[c4+3].z * x3.z + Wr[c4+3].w * x3.w;
        }
        float acc = (a0 + a1) + (a2 + a3) + x[(size_t)(s0 + s) * 96 + e];
        out[(size_t)(s0 + s) * 96 + e] = acc;
    }
}

extern "C" void kernel_launch(void* const* d_in, const int* in_sizes, int n_in,
                              void* d_out, int out_size, void* d_ws, size_t ws_size,
                              hipStream_t stream) {
    const float* x        = (const float*)d_in[0];
    const float* ln1_w    = (const float*)d_in[1];
    const float* ln1_b    = (const float*)d_in[2];
    const float* in_proj  = (const float*)d_in[3];
    const float* conv_w   = (const float*)d_in[4];
    const float* conv_b   = (const float*)d_in[5];
    const float* x_proj   = (const float*)d_in[6];
    const float* dt_w     = (const float*)d_in[7];
    const float* dt_b     = (const float*)d_in[8];
    const float* A_log    = (const float*)d_in[9];
    const float* D_skip   = (const float*)d_in[10];
    const float* onw      = (const float*)d_in[11];
    const float* onb      = (const float*)d_in[12];
    const float* out_w    = (const float*)d_in[13];
    float* out = (float*)d_out;

    _Float16* xhh  = (_Float16*)d_ws;                 // 96*4096
    _Float16* zsh  = xhh + (size_t)96 * L;            // 4096*96
    _Float16* xch  = zsh + (size_t)96 * L;            // 96*4096
    _Float16* xcTh = xch + (size_t)96 * L;            // 4096*96
    _Float16* Y2h  = xcTh + (size_t)96 * L;           // 6*4096*32
    _Float16* Zsh  = Y2h + (size_t)KDIR * L * YH;     // 6*4096*96
    _Float16* ysh  = Zsh + (size_t)KDIR * L * 96;     // 4096*6*96
    _Float16* Aah  = ysh + (size_t)L * KDIR * 96;     // 6*256*96*16
    _Float16* Abh  = Aah + (size_t)KDIR * NCHUNK * DDIM * NST;
    _Float16* Pbh  = Abh + (size_t)KDIR * NCHUNK * DDIM * NST;

    k1_ln_inproj<<<dim3(L / 8), dim3(192), 0, stream>>>(x, ln1_w, ln1_b, in_proj, xhh, zsh);
    k2_conv<<<dim3(96 * L / 256), dim3(256), 0, stream>>>(xhh, conv_w, conv_b, xch, xcTh);
    k3_xproj<<<dim3(KDIR, 16, 4), dim3(256), 0, stream>>>(xch, x_proj, dt_w, dt_b, Y2h, Zsh);
    ka_scan<<<dim3(KDIR * NCHUNK * DDIM * 4 / 256), dim3(256), 0, stream>>>(Zsh, xcTh, Y2h, A_log, Aah, Abh);
    kb_combine<<<dim3(KDIR * DDIM * NST / 256), dim3(256), 0, stream>>>(Aah, Abh, Pbh);
    kc_apply<<<dim3(KDIR * NCHUNK * DDIM * 4 / 256), dim3(256), 0, stream>>>(Zsh, xcTh, Y2h, A_log, D_skip, Pbh, ysh);
    k6_out<<<dim3(L / 8), dim3(192), 0, stream>>>(ysh, zsh, onw, onb, out_w, x, out);
}

// Round 9
// 180.955 us; speedup vs baseline: 2.1105x; 1.0496x over previous
//
#include <hip/hip_runtime.h>
#include <hip/hip_bf16.h>

// Sizes (fixed): B=1, D=H=W=16 -> L=4096, C=96, d=96, K=6, N=16, R=6
#define L 4096
#define CDIM 96
#define DDIM 96
#define KDIR 6
#define NST 16
#define RRK 6
#define YH 32        // Y2h row: B at [0..15], C at [16..31] (half)
#define NCHUNK 256
#define CHLEN 16     // NCHUNK*CHLEN == L

typedef _Float16 half4v __attribute__((ext_vector_type(4)));

__device__ __forceinline__ float sigmoidf_(float x) { return 1.f / (1.f + __expf(-x)); }

// scan-position l -> spatial index s for base direction kb in {0,1,2}
__device__ __forceinline__ int sigma_k(int kb, int l) {
    if (kb == 0) return l;
    if (kb == 1) return ((l & 15) << 8) | ((l >> 8) << 4) | ((l >> 4) & 15);
    return (((l >> 4) & 15) << 8) | ((l & 15) << 4) | (l >> 8);
}

// K1: LN + in_proj, weight-in-registers, 8 spatial rows per block.
__global__ void __launch_bounds__(192) k1_ln_inproj(
        const float* __restrict__ x, const float* __restrict__ ln_w,
        const float* __restrict__ ln_b, const float* __restrict__ Wp,
        _Float16* __restrict__ xhh, _Float16* __restrict__ zsh) {
    int s0 = blockIdx.x * 8;
    int tid = threadIdx.x;
    __shared__ __align__(16) float xt[8][96];
    __shared__ __align__(16) float xn[8][96];
    __shared__ float mss[8], rss[8];
    ((float4*)&xt[0][0])[tid] = ((const float4*)(x + (size_t)s0 * 96))[tid];
    __syncthreads();
    int wave = tid >> 6, lane = tid & 63;
    for (int r = wave; r < 8; r += 3) {
        float v = xt[r][lane] + ((lane < 32) ? xt[r][64 + lane] : 0.f);
#pragma unroll
        for (int off = 1; off < 64; off <<= 1) v += __shfl_xor(v, off);
        float vs = xt[r][lane] * xt[r][lane] + ((lane < 32) ? xt[r][64 + lane] * xt[r][64 + lane] : 0.f);
#pragma unroll
        for (int off = 1; off < 64; off <<= 1) vs += __shfl_xor(vs, off);
        if (lane == 0) {
            float mean = v * (1.f / 96.f);
            float var = vs * (1.f / 96.f) - mean * mean;
            mss[r] = mean; rss[r] = rsqrtf(var + 1e-6f);
        }
    }
    __syncthreads();
    {
        int r = tid / 24, c4 = tid % 24;
        float4 xv = ((float4*)&xt[r][0])[c4];
        float4 wv = ((const float4*)ln_w)[c4];
        float4 bv = ((const float4*)ln_b)[c4];
        float m = mss[r], rs = rss[r];
        float4 o;
        o.x = (xv.x - m) * rs * wv.x + bv.x;
        o.y = (xv.y - m) * rs * wv.y + bv.y;
        o.z = (xv.z - m) * rs * wv.z + bv.z;
        o.w = (xv.w - m) * rs * wv.w + bv.w;
        ((float4*)&xn[r][0])[c4] = o;
    }
    float4 Wr[24];
    const float4* wr = (const float4*)(Wp + (size_t)tid * 96);
#pragma unroll
    for (int c4 = 0; c4 < 24; c4++) Wr[c4] = wr[c4];
    __syncthreads();
#pragma unroll
    for (int s = 0; s < 8; s++) {
        const float4* xr4 = (const float4*)&xn[s][0];
        float a0 = 0.f, a1 = 0.f, a2 = 0.f, a3 = 0.f;
#pragma unroll
        for (int c4 = 0; c4 < 24; c4 += 4) {
            float4 x0 = xr4[c4], x1 = xr4[c4 + 1], x2 = xr4[c4 + 2], x3 = xr4[c4 + 3];
            a0 += Wr[c4].x * x0.x + Wr[c4].y * x0.y + Wr[c4].z * x0.z + Wr[c4].w * x0.w;
            a1 += Wr[c4+1].x * x1.x + Wr[c4+1].y * x1.y + Wr[c4+1].z * x1.z + Wr[c4+1].w * x1.w;
            a2 += Wr[c4+2].x * x2.x + Wr[c4+2].y * x2.y + Wr[c4+2].z * x2.z + Wr[c4+2].w * x2.w;
            a3 += Wr[c4+3].x * x3.x + Wr[c4+3].y * x3.y + Wr[c4+3].z * x3.z + Wr[c4+3].w * x3.w;
        }
        float acc = (a0 + a1) + (a2 + a3);
        if (tid < 96) xhh[(size_t)tid * L + s0 + s] = (_Float16)acc;
        else zsh[(size_t)(s0 + s) * 96 + (tid - 96)] = (_Float16)(acc * sigmoidf_(acc));
    }
}

// K2: depthwise 3x3x3 conv (SAME) + bias + SiLU; writes xch[c][s] and xcTh[s][c]
__global__ void k2_conv(const _Float16* __restrict__ xhh, const float* __restrict__ cw,
                        const float* __restrict__ cb, _Float16* __restrict__ xch,
                        _Float16* __restrict__ xcTh) {
    int idx = blockIdx.x * 256 + threadIdx.x; // 96*4096
    int c = idx >> 12, s = idx & 4095;
    int dz = s >> 8, h = (s >> 4) & 15, w = s & 15;
    const _Float16* xin = xhh + (size_t)c * L;
    const float* wc = cw + c * 27;
    float acc = cb[c];
#pragma unroll
    for (int i = 0; i < 3; i++) {
        int z2 = dz + i - 1; if ((unsigned)z2 > 15u) continue;
#pragma unroll
        for (int j = 0; j < 3; j++) {
            int h2 = h + j - 1; if ((unsigned)h2 > 15u) continue;
#pragma unroll
            for (int kk = 0; kk < 3; kk++) {
                int w2 = w + kk - 1; if ((unsigned)w2 > 15u) continue;
                acc += (float)xin[z2 * 256 + h2 * 16 + w2] * wc[i * 9 + j * 3 + kk];
            }
        }
    }
    float r = acc * sigmoidf_(acc);
    _Float16 hr = (_Float16)r;
    xch[(size_t)c * L + s] = hr;
    xcTh[(size_t)s * 96 + c] = hr;
}

// K3 (+fused K4, balanced): grid (6,16,4). Group g computes the 6 dt channels
// (redundantly) + 8 B/C channels (x_proj channels 6+g*8 .. 13+g*8), then
// expands dt -> Zsh for its own 24-of-96 d-range. All blocks do equal work.
__global__ void k3_xproj(const _Float16* __restrict__ xch, const float* __restrict__ Wx,
                         const float* __restrict__ Wdt, const float* __restrict__ bdt,
                         _Float16* __restrict__ Y2h, _Float16* __restrict__ Zsh) {
    int k = blockIdx.x;
    int tid = threadIdx.x;
    int sbase = blockIdx.y * 256;
    int s = sbase + tid;
    int g = blockIdx.z;   // 0..3
    __shared__ float dts[256][6];
    float acc[14];
#pragma unroll
    for (int i = 0; i < 14; i++) acc[i] = 0.f;
    const float* wdt_rows = Wx + (size_t)k * 38 * DDIM;                 // channels 0..5
    const float* wbc      = Wx + ((size_t)k * 38 + 6 + g * 8) * DDIM;   // 8 B/C channels
    for (int dd = 0; dd < 96; dd += 4) {
        float v[4];
#pragma unroll
        for (int j = 0; j < 4; j++) v[j] = (float)xch[(size_t)(dd + j) * L + s];
#pragma unroll
        for (int j = 0; j < 4; j++) {
#pragma unroll
            for (int r = 0; r < 6; r++) acc[r] += wdt_rows[r * DDIM + dd + j] * v[j];
#pragma unroll
            for (int i = 0; i < 8; i++) acc[6 + i] += wbc[i * DDIM + dd + j] * v[j];
        }
    }
    _Float16* yo = Y2h + ((size_t)k * L + s) * YH;
#pragma unroll
    for (int i = 0; i < 8; i++) yo[g * 8 + i] = (_Float16)acc[6 + i];
#pragma unroll
    for (int r = 0; r < 6; r++) dts[tid][r] = acc[r];
    __syncthreads();
    // expand d in [g*24, g*24+24): Zsh[k][sbase+sr][d] = softplus(bdt + Wdt·dt)
    for (int i = 0; i < 24; i++) {
        int idx = i * 256 + tid;      // < 6144 = 256 sr * 24 dl
        int dl = idx % 24;
        int sr = idx / 24;
        int d = g * 24 + dl;
        const float* wr = Wdt + ((size_t)k * 96 + d) * 6;
        float a = bdt[k * 96 + d];
#pragma unroll
        for (int r = 0; r < 6; r++) a += wr[r] * dts[sr][r];
        float sp = (a > 15.f) ? a : __logf(1.f + __expf(a));
        Zsh[((size_t)k * L + sbase + sr) * 96 + d] = (_Float16)sp;
    }
}

// ---- 3-phase chunked scan, 4 states/thread (nq = t&3), fp16 everywhere ----
// thread t: nq = t&3, d = (t>>2)%96, chunk = ((t>>2)/96)%NCHUNK, k = (t>>2)/(96*NCHUNK)

__global__ void __launch_bounds__(256) ka_scan(
        const _Float16* __restrict__ Zsh, const _Float16* __restrict__ xcTh,
        const _Float16* __restrict__ Y2h, const float* __restrict__ A_log,
        _Float16* __restrict__ Aah, _Float16* __restrict__ Abh) {
    int t = blockIdx.x * 256 + threadIdx.x;
    int nq = t & 3;
    int q = t >> 2;
    int d = q % 96;
    int rest = q / 96;
    int chunk = rest % NCHUNK;
    int k = rest / NCHUNK;
    int kb = (k < 3) ? k : (k - 3);
    bool flip = (k >= 3);
    float An[4];
    {
        float4 al = *(const float4*)(A_log + ((size_t)k * 96 + d) * 16 + nq * 4);
        An[0] = -__expf(al.x); An[1] = -__expf(al.y);
        An[2] = -__expf(al.z); An[3] = -__expf(al.w);
    }
    float a[4] = {1.f, 1.f, 1.f, 1.f};
    float b[4] = {0.f, 0.f, 0.f, 0.f};
    const _Float16* Zk = Zsh + (size_t)k * L * 96;
    const _Float16* Yk = Y2h + (size_t)k * L * YH;
    int l0 = chunk * CHLEN;
    for (int i = 0; i < CHLEN; i += 4) {
        int sI[4]; float dt[4], xv[4]; half4v Bh[4];
#pragma unroll
        for (int j = 0; j < 4; j++) {
            int l = l0 + i + j;
            int lp = flip ? (4095 - l) : l;
            sI[j] = sigma_k(kb, lp);
        }
#pragma unroll
        for (int j = 0; j < 4; j++) {
            dt[j] = (float)Zk[(size_t)sI[j] * 96 + d];
            xv[j] = (float)xcTh[(size_t)sI[j] * 96 + d];
            Bh[j] = *(const half4v*)(Yk + (size_t)sI[j] * YH + nq * 4);
        }
#pragma unroll
        for (int j = 0; j < 4; j++) {
            float dtx = dt[j] * xv[j];
            float e0 = __expf(dt[j] * An[0]);
            float e1 = __expf(dt[j] * An[1]);
            float e2 = __expf(dt[j] * An[2]);
            float e3 = __expf(dt[j] * An[3]);
            b[0] = e0 * b[0] + dtx * (float)Bh[j].x; a[0] *= e0;
            b[1] = e1 * b[1] + dtx * (float)Bh[j].y; a[1] *= e1;
            b[2] = e2 * b[2] + dtx * (float)Bh[j].z; a[2] *= e2;
            b[3] = e3 * b[3] + dtx * (float)Bh[j].w; a[3] *= e3;
        }
    }
    size_t o = (((size_t)k * NCHUNK + chunk) * 96 + d) * 16 + nq * 4;
    half4v ha, hb;
    ha.x = (_Float16)a[0]; ha.y = (_Float16)a[1]; ha.z = (_Float16)a[2]; ha.w = (_Float16)a[3];
    hb.x = (_Float16)b[0]; hb.y = (_Float16)b[1]; hb.z = (_Float16)b[2]; hb.w = (_Float16)b[3];
    *(half4v*)(Aah + o) = ha;
    *(half4v*)(Abh + o) = hb;
}

// Phase B: serial combine across 256 chunks per (k,d,n); fp16 in/out
__global__ void __launch_bounds__(256) kb_combine(
        const _Float16* __restrict__ Aah, const _Float16* __restrict__ Abh,
        _Float16* __restrict__ Pbh) {
    int t = blockIdx.x * 256 + threadIdx.x;  // < 6*96*16 = 9216
    int n = t & 15;
    int rest = t >> 4;
    int d = rest % 96;
    int k = rest / 96;
    size_t base = ((size_t)k * NCHUNK * 96 + d) * 16 + n;
    const size_t cstride = 96 * 16;
    float rb = 0.f;
    for (int c0 = 0; c0 < NCHUNK; c0 += 16) {
        float av[16], bv[16];
#pragma unroll
        for (int j = 0; j < 16; j++) {
            av[j] = (float)Aah[base + (size_t)(c0 + j) * cstride];
            bv[j] = (float)Abh[base + (size_t)(c0 + j) * cstride];
        }
#pragma unroll
        for (int j = 0; j < 16; j++) {
            Pbh[base + (size_t)(c0 + j) * cstride] = (_Float16)rb;
            rb = av[j] * rb + bv[j];
        }
    }
}

// Phase C: re-scan with carry, fuse y = sum_n h*C + D*x; ysh layout [s][k][d] (half)
__global__ void __launch_bounds__(256) kc_apply(
        const _Float16* __restrict__ Zsh, const _Float16* __restrict__ xcTh,
        const _Float16* __restrict__ Y2h, const float* __restrict__ A_log,
        const float* __restrict__ D_skip, const _Float16* __restrict__ Pbh,
        _Float16* __restrict__ ysh) {
    int t = blockIdx.x * 256 + threadIdx.x;
    int nq = t & 3;
    int q = t >> 2;
    int d = q % 96;
    int rest = q / 96;
    int chunk = rest % NCHUNK;
    int k = rest / NCHUNK;
    int kb = (k < 3) ? k : (k - 3);
    bool flip = (k >= 3);
    float An[4];
    {
        float4 al = *(const float4*)(A_log + ((size_t)k * 96 + d) * 16 + nq * 4);
        An[0] = -__expf(al.x); An[1] = -__expf(al.y);
        An[2] = -__expf(al.z); An[3] = -__expf(al.w);
    }
    float Dk = D_skip[k * DDIM + d];
    float h[4];
    {
        half4v hp = *(const half4v*)(Pbh + (((size_t)k * NCHUNK + chunk) * 96 + d) * 16 + nq * 4);
        h[0] = (float)hp.x; h[1] = (float)hp.y; h[2] = (float)hp.z; h[3] = (float)hp.w;
    }
    const _Float16* Zk = Zsh + (size_t)k * L * 96;
    const _Float16* Yk = Y2h + (size_t)k * L * YH;
    int l0 = chunk * CHLEN;
    for (int i = 0; i < CHLEN; i += 4) {
        int sI[4]; float dt[4], xv[4]; half4v Bh[4], Ch[4];
#pragma unroll
        for (int j = 0; j < 4; j++) {
            int l = l0 + i + j;
            int lp = flip ? (4095 - l) : l;
            sI[j] = sigma_k(kb, lp);
        }
#pragma unroll
        for (int j = 0; j < 4; j++) {
            dt[j] = (float)Zk[(size_t)sI[j] * 96 + d];
            xv[j] = (float)xcTh[(size_t)sI[j] * 96 + d];
            Bh[j] = *(const half4v*)(Yk + (size_t)sI[j] * YH + nq * 4);
            Ch[j] = *(const half4v*)(Yk + (size_t)sI[j] * YH + 16 + nq * 4);
        }
#pragma unroll
        for (int j = 0; j < 4; j++) {
            float dtx = dt[j] * xv[j];
            float e0 = __expf(dt[j] * An[0]);
            float e1 = __expf(dt[j] * An[1]);
            float e2 = __expf(dt[j] * An[2]);
            float e3 = __expf(dt[j] * An[3]);
            h[0] = e0 * h[0] + dtx * (float)Bh[j].x;
            h[1] = e1 * h[1] + dtx * (float)Bh[j].y;
            h[2] = e2 * h[2] + dtx * (float)Bh[j].z;
            h[3] = e3 * h[3] + dtx * (float)Bh[j].w;
            float p = h[0] * (float)Ch[j].x + h[1] * (float)Ch[j].y
                    + h[2] * (float)Ch[j].z + h[3] * (float)Ch[j].w;
            p += __shfl_xor(p, 1);
            p += __shfl_xor(p, 2);
            if (nq == 0) ysh[((size_t)sI[j] * KDIR + k) * 96 + d] = (_Float16)(p + Dk * xv[j]);
        }
    }
}

// K6: weight-in-registers out stage. 8 s-rows per block, 192 thr, grid 512.
__global__ void __launch_bounds__(192) k6_out(
        const _Float16* __restrict__ ysh, const _Float16* __restrict__ zsh,
        const float* __restrict__ onw, const float* __restrict__ onb,
        const float* __restrict__ Wo, const float* __restrict__ x,
        float* __restrict__ out) {
    int s0 = blockIdx.x * 8;
    int tid = threadIdx.x;
    __shared__ __align__(16) float vt[8][96];
    __shared__ __align__(16) float gt[8][96];
    __shared__ float mss[8], rss[8];
#pragma unroll
    for (int j = 0; j < 4; j++) {
        int f = tid + j * 192;           // < 768
        int sr = f / 96, c = f % 96;
        const _Float16* yr = ysh + ((size_t)(s0 + sr) * KDIR) * 96 + c;
        float v = 0.f;
#pragma unroll
        for (int k = 0; k < KDIR; k++) v += (float)yr[k * 96];
        vt[sr][c] = v;
    }
    __syncthreads();
    int wave = tid >> 6, lane = tid & 63;
    for (int r = wave; r < 8; r += 3) {
        float v = vt[r][lane] + ((lane < 32) ? vt[r][64 + lane] : 0.f);
#pragma unroll
        for (int off = 1; off < 64; off <<= 1) v += __shfl_xor(v, off);
        float vs = vt[r][lane] * vt[r][lane] + ((lane < 32) ? vt[r][64 + lane] * vt[r][64 + lane] : 0.f);
#pragma unroll
        for (int off = 1; off < 64; off <<= 1) vs += __shfl_xor(vs, off);
        if (lane == 0) {
            float mean = v * (1.f / 96.f);
            float var = vs * (1.f / 96.f) - mean * mean;
            mss[r] = mean; rss[r] = rsqrtf(var + 1e-5f);
        }
    }
    __syncthreads();
#pragma unroll
    for (int j = 0; j < 4; j++) {
        int f = tid + j * 192;
        int sr = f / 96, c = f % 96;
        float g = (vt[sr][c] - mss[sr]) * rss[sr] * onw[c] + onb[c];
        gt[sr][c] = g * (float)zsh[(size_t)(s0 + sr) * 96 + c];
    }
    int e = tid % 96, sg = tid / 96;  // sg in {0,1}
    float4 Wr[24];
    const float4* wr = (const float4*)(Wo + (size_t)e * 96);
#pragma unroll
    for (int c4 = 0; c4 < 24; c4++) Wr[c4] = wr[c4];
    __syncthreads();
#pragma unroll
    for (int j = 0; j < 4; j++) {
        int s = sg * 4 + j;
        const float4* g4 = (const float4*)&gt[s][0];
        float a0 = 0.f, a1 = 0.f, a2 = 0.f, a3 = 0.f;
#pragma unroll
        for (int c4 = 0; c4 < 24; c4 += 4) {
            float4 x0 = g4[c4], x1 = g4[c4 + 1], x2 = g4[c4 + 2], x3 = g4[c4 + 3];
            a0 += Wr[c4].x * x0.x + Wr[c4].y * x0.y + Wr[c4].z * x0.z + Wr[c4].w * x0.w;
            a1 += Wr[c4+1].x * x1.x + Wr[c4+1].y * x1.y + Wr[c4+1].z * x1.z + Wr[c4+1].w * x1.w;
            a2 += Wr[c4+2].x * x2.x + Wr[c4+2].y * x2.y + Wr[c4+2].z * x2.z + Wr[c4+2].w * x2.w;
            a3 += Wr[c4+3].x * x3.x + Wr[c4+3].y * x3.y + Wr[c4+3].z * x3.z + Wr[c4+3].w * x3.w;
        }
        float acc = (a0 + a1) + (a2 + a3) + x[(size_t)(s0 + s) * 96 + e];
        out[(size_t)(s0 + s) * 96 + e] = acc;
    }
}

extern "C" void kernel_launch(void* const* d_in, const int* in_sizes, int n_in,
                              void* d_out, int out_size, void* d_ws, size_t ws_size,
                              hipStream_t stream) {
    const float* x        = (const float*)d_in[0];
    const float* ln1_w    = (const float*)d_in[1];
    const float* ln1_b    = (const float*)d_in[2];
    const float* in_proj  = (const float*)d_in[3];
    const float* conv_w   = (const float*)d_in[4];
    const float* conv_b   = (const float*)d_in[5];
    const float* x_proj   = (const float*)d_in[6];
    const float* dt_w     = (const float*)d_in[7];
    const float* dt_b     = (const float*)d_in[8];
    const float* A_log    = (const float*)d_in[9];
    const float* D_skip   = (const float*)d_in[10];
    const float* onw      = (const float*)d_in[11];
    const float* onb      = (const float*)d_in[12];
    const float* out_w    = (const float*)d_in[13];
    float* out = (float*)d_out;

    _Float16* xhh  = (_Float16*)d_ws;                 // 96*4096
    _Float16* zsh  = xhh + (size_t)96 * L;            // 4096*96
    _Float16* xch  = zsh + (size_t)96 * L;            // 96*4096
    _Float16* xcTh = xch + (size_t)96 * L;            // 4096*96
    _Float16* Y2h  = xcTh + (size_t)96 * L;           // 6*4096*32
    _Float16* Zsh  = Y2h + (size_t)KDIR * L * YH;     // 6*4096*96
    _Float16* ysh  = Zsh + (size_t)KDIR * L * 96;     // 4096*6*96
    _Float16* Aah  = ysh + (size_t)L * KDIR * 96;     // 6*256*96*16
    _Float16* Abh  = Aah + (size_t)KDIR * NCHUNK * DDIM * NST;
    _Float16* Pbh  = Abh + (size_t)KDIR * NCHUNK * DDIM * NST;

    k1_ln_inproj<<<dim3(L / 8), dim3(192), 0, stream>>>(x, ln1_w, ln1_b, in_proj, xhh, zsh);
    k2_conv<<<dim3(96 * L / 256), dim3(256), 0, stream>>>(xhh, conv_w, conv_b, xch, xcTh);
    k3_xproj<<<dim3(KDIR, 16, 4), dim3(256), 0, stream>>>(xch, x_proj, dt_w, dt_b, Y2h, Zsh);
    ka_scan<<<dim3(KDIR * NCHUNK * DDIM * 4 / 256), dim3(256), 0, stream>>>(Zsh, xcTh, Y2h, A_log, Aah, Abh);
    kb_combine<<<dim3(KDIR * DDIM * NST / 256), dim3(256), 0, stream>>>(Aah, Abh, Pbh);
    kc_apply<<<dim3(KDIR * NCHUNK * DDIM * 4 / 256), dim3(256), 0, stream>>>(Zsh, xcTh, Y2h, A_log, D_skip, Pbh, ysh);
    k6_out<<<dim3(L / 8), dim3(192), 0, stream>>>(ysh, zsh, onw, onb, out_w, x, out);
}